// Round 2
// baseline (742.490 us; speedup 1.0000x reference)
//
#include <hip/hip_runtime.h>
#include <hip/hip_bf16.h>
#include <math.h>

#define NHEADS   32
#define CONV_DIM 2304
#define D_INNER  2048
#define SEQLEN   1024
#define NROWS    2048     // BATCH*SEQLEN
#define ZX_STR   4352     // z(2048) + xBC(2304); dt columns handled separately
#define D_MODEL  1024

typedef __attribute__((ext_vector_type(8))) short bhalf8;
typedef __attribute__((ext_vector_type(4))) float f32x4;

__device__ __forceinline__ float bf2f(__hip_bfloat16 v){ return __bfloat162float(v); }
__device__ __forceinline__ short f2bs(float f){ __hip_bfloat16 h = __float2bfloat16(f); return *(short*)&h; }
// dtype-flag-aware scalar read of a raw input tensor (isf=1 -> fp32, 0 -> bf16)
__device__ __forceinline__ float rdin(const void* p, size_t i, int isf){
    return isf ? ((const float*)p)[i] : __bfloat162float(((const __hip_bfloat16*)p)[i]);
}

// ---------------------------------------------------------------------------
// Dtype detection: view x as ushort; even-indexed elements are real bf16 values
// (sane exponents) iff the tensor is bf16; if fp32 they are mantissa-low halves
// (random exponents). Vote over 4096 samples. flag=1 => fp32.
// ---------------------------------------------------------------------------
__global__ __launch_bounds__(256)
void detect_dtype(const unsigned short* __restrict__ p, int* __restrict__ flag)
{
    int cnt = 0;
    for (int i = threadIdx.x; i < 4096; i += 256) {
        unsigned short u = p[2 * i];
        int e = (u >> 7) & 0xFF;
        cnt += (e >= 90 && e <= 141) ? 1 : 0;
    }
#pragma unroll
    for (int m = 1; m < 64; m <<= 1) cnt += __shfl_xor(cnt, m);
    __shared__ int red[4];
    if ((threadIdx.x & 63) == 0) red[threadIdx.x >> 6] = cnt;
    __syncthreads();
    if (threadIdx.x == 0) {
        int tot = red[0] + red[1] + red[2] + red[3];
        *flag = (tot < 2048) ? 1 : 0;
    }
}

// ---------------------------------------------------------------------------
// Normalize an input tensor to a canonical bf16 buffer (16B per thread).
// n8 = element_count / 8.
// ---------------------------------------------------------------------------
typedef __attribute__((ext_vector_type(8))) short short8;
__global__ __launch_bounds__(256)
void to_bf16(const void* __restrict__ src, __hip_bfloat16* __restrict__ dst,
             int n8, const int* __restrict__ flagp)
{
    const int isf = *flagp;
    int i = blockIdx.x * 256 + threadIdx.x;
    if (i >= n8) return;
    if (isf) {
        const float4* s = (const float4*)src;
        float4 a = s[2 * i], b = s[2 * i + 1];
        short8 r;
        r[0] = f2bs(a.x); r[1] = f2bs(a.y); r[2] = f2bs(a.z); r[3] = f2bs(a.w);
        r[4] = f2bs(b.x); r[5] = f2bs(b.y); r[6] = f2bs(b.z); r[7] = f2bs(b.w);
        ((short8*)dst)[i] = r;
    } else {
        ((float4*)dst)[i] = ((const float4*)src)[i];   // raw 16B copy
    }
}

// ---------------------------------------------------------------------------
// C[m,n] = sum_k A[m,k]*W[n,k], A/W bf16 canon. 128x128 tile, BK=64, 4 waves.
// MODE 0: store bf16 to Cb (stride N). MODE 1: +resid, flag-dtype store to outv.
// ---------------------------------------------------------------------------
template<int MODE>
__global__ __launch_bounds__(256)
void gemm_bt(const __hip_bfloat16* __restrict__ A,
             const __hip_bfloat16* __restrict__ W,
             __hip_bfloat16* __restrict__ Cb,
             const __hip_bfloat16* __restrict__ resid,
             void* __restrict__ outv,
             const int* __restrict__ flagp,
             int K, int N)
{
    __shared__ short As[128 * 64];
    __shared__ short Bs[128 * 64];
    const int m0 = blockIdx.y * 128;
    const int n0 = blockIdx.x * 128;
    const int wave = threadIdx.x >> 6;
    const int lane = threadIdx.x & 63;
    const int lr8 = lane >> 3, lc8 = lane & 7;
    const int lr  = lane & 15, lq  = lane >> 4;
    const int wm = (wave & 1) * 64, wn = (wave >> 1) * 64;

    f32x4 acc[4][4];
#pragma unroll
    for (int i = 0; i < 4; ++i)
#pragma unroll
        for (int j = 0; j < 4; ++j) acc[i][j] = (f32x4){0.f, 0.f, 0.f, 0.f};

    for (int k0 = 0; k0 < K; k0 += 64) {
#pragma unroll
        for (int i = 0; i < 4; ++i) {
            const int rt = wave * 32 + i * 8;
            const __hip_bfloat16* gp = A + (size_t)(m0 + rt + lr8) * K + k0 + lc8 * 8;
            __builtin_amdgcn_global_load_lds(
                (const __attribute__((address_space(1))) void*)gp,
                (__attribute__((address_space(3))) void*)&As[rt * 64], 16, 0, 0);
        }
#pragma unroll
        for (int i = 0; i < 4; ++i) {
            const int rt = wave * 32 + i * 8;
            const __hip_bfloat16* gp = W + (size_t)(n0 + rt + lr8) * K + k0 + lc8 * 8;
            __builtin_amdgcn_global_load_lds(
                (const __attribute__((address_space(1))) void*)gp,
                (__attribute__((address_space(3))) void*)&Bs[rt * 64], 16, 0, 0);
        }
        __syncthreads();
#pragma unroll
        for (int kk = 0; kk < 64; kk += 32) {
            bhalf8 af[4], bfv[4];
#pragma unroll
            for (int t = 0; t < 4; ++t)
                af[t]  = *(const bhalf8*)&As[(wm + t * 16 + lr) * 64 + kk + lq * 8];
#pragma unroll
            for (int t = 0; t < 4; ++t)
                bfv[t] = *(const bhalf8*)&Bs[(wn + t * 16 + lr) * 64 + kk + lq * 8];
#pragma unroll
            for (int ti = 0; ti < 4; ++ti)
#pragma unroll
                for (int tj = 0; tj < 4; ++tj)
                    acc[ti][tj] = __builtin_amdgcn_mfma_f32_16x16x32_bf16(
                        af[ti], bfv[tj], acc[ti][tj], 0, 0, 0);
        }
        __syncthreads();
    }

    const int isf = (MODE == 1) ? *flagp : 0;
#pragma unroll
    for (int ti = 0; ti < 4; ++ti)
#pragma unroll
        for (int tj = 0; tj < 4; ++tj)
#pragma unroll
            for (int r = 0; r < 4; ++r) {
                int m = m0 + wm + ti * 16 + lq * 4 + r;
                int n = n0 + wn + tj * 16 + lr;
                size_t idx = (size_t)m * N + n;
                float v = acc[ti][tj][r];
                if (MODE == 0) {
                    Cb[idx] = __float2bfloat16(v);
                } else {
                    v += bf2f(resid[idx]);
                    if (isf) ((float*)outv)[idx] = v;
                    else     ((__hip_bfloat16*)outv)[idx] = __float2bfloat16(v);
                }
            }
}

// ---------------------------------------------------------------------------
// dt path in full fp32 from RAW inputs (avoids bf16 error amplified by
// 1/(1-dA) in the recurrence): dt_raw[m,h] = x[m,:]·W[4352+h,:] + dt_bias[h];
// dtp = softplus(dt_raw); dAb = exp(dtp * -exp(A_log)). One block per row.
// ---------------------------------------------------------------------------
__global__ __launch_bounds__(256)
void dt_kernel(const void* __restrict__ xraw, const void* __restrict__ wraw,
               const void* __restrict__ dt_bias, const void* __restrict__ A_log,
               const int* __restrict__ flagp,
               float* __restrict__ dtp, float* __restrict__ dAb)
{
    const int isf = *flagp;
    const int row = blockIdx.x;
    __shared__ float xs[D_MODEL];
    for (int k = threadIdx.x; k < D_MODEL; k += 256)
        xs[k] = rdin(xraw, (size_t)row * D_MODEL + k, isf);
    __syncthreads();
    const int h = threadIdx.x >> 3;   // 32 heads
    const int t = threadIdx.x & 7;    // 8 threads/head
    const size_t wbase = (size_t)(4352 + h) * D_MODEL;
    float s = 0.f;
    for (int k = t; k < D_MODEL; k += 8)
        s += xs[k] * rdin(wraw, wbase + k, isf);
    s += __shfl_xor(s, 1);
    s += __shfl_xor(s, 2);
    s += __shfl_xor(s, 4);
    if (t == 0) {
        float raw = s + rdin(dt_bias, h, isf);
        float sp = raw > 20.f ? raw : log1pf(expf(raw));
        float An = -expf(rdin(A_log, h, isf));
        dtp[(size_t)row * NHEADS + h] = sp;
        dAb[(size_t)row * NHEADS + h] = expf(sp * An);
    }
}

// ---------------------------------------------------------------------------
// Depthwise causal conv(4) + bias + SiLU on the xBC slice of zxb (bf16).
// ---------------------------------------------------------------------------
__global__ __launch_bounds__(256)
void conv_silu(const __hip_bfloat16* __restrict__ zxb,
               const void* __restrict__ conv_w, const void* __restrict__ conv_b,
               const int* __restrict__ flagp, float* __restrict__ xBCc)
{
    const int isf = *flagp;
    const int row = blockIdx.x;
    const int l = row & (SEQLEN - 1);
    for (int c = threadIdx.x; c < CONV_DIM; c += 256) {
        float acc = rdin(conv_b, c, isf);
#pragma unroll
        for (int j = 0; j < 4; ++j) {
            int ls = l - 3 + j;
            if (ls >= 0)
                acc += bf2f(zxb[(size_t)(row - 3 + j) * ZX_STR + 2048 + c]) *
                       rdin(conv_w, (size_t)c * 4 + j, isf);
        }
        xBCc[(size_t)row * CONV_DIM + c] = acc / (1.f + expf(-acc));
    }
}

// ---------------------------------------------------------------------------
// Selective scan. Grid 256 = B(2) x H(32) x Pchunk(4); block 256.
// Thread: p = pc*16 + (tid>>4); n-slice = (tid&15)*8..+8. State in registers,
// next-step register prefetch, 16-lane shuffle reduce for y.
// ---------------------------------------------------------------------------
__global__ __launch_bounds__(256)
void scan_kernel(const float* __restrict__ xBCc,
                 const float* __restrict__ dtp,
                 const float* __restrict__ dAb,
                 const void* __restrict__ Draw,
                 const int* __restrict__ flagp,
                 float* __restrict__ yws)
{
    const int isf = *flagp;
    const int b  = blockIdx.x >> 7;
    const int h  = (blockIdx.x >> 2) & 31;
    const int pc = blockIdx.x & 3;
    const int g  = threadIdx.x & 15;
    const int pl = threadIdx.x >> 4;
    const int p  = pc * 16 + pl;

    const float* base = xBCc + (size_t)(b << 10) * CONV_DIM;
    const float Dh = rdin(Draw, h, isf);

    float hs[8];
#pragma unroll
    for (int j = 0; j < 8; ++j) hs[j] = 0.f;

    float dt_c, dA_c, x_c;
    float4 B_c[2], C_c[2];
    {
        const float* r = base;
        x_c = r[h * 64 + p];
        B_c[0] = *(const float4*)(r + 2048 + g * 8);
        B_c[1] = *(const float4*)(r + 2048 + g * 8 + 4);
        C_c[0] = *(const float4*)(r + 2176 + g * 8);
        C_c[1] = *(const float4*)(r + 2176 + g * 8 + 4);
        int idx = (b << 10) * NHEADS + h;
        dt_c = dtp[idx]; dA_c = dAb[idx];
    }

    for (int l = 0; l < SEQLEN; ++l) {
        int ln = (l + 1 < SEQLEN) ? l + 1 : SEQLEN - 1;
        const float* r = base + (size_t)ln * CONV_DIM;
        float x_n = r[h * 64 + p];
        float4 B_n0 = *(const float4*)(r + 2048 + g * 8);
        float4 B_n1 = *(const float4*)(r + 2048 + g * 8 + 4);
        float4 C_n0 = *(const float4*)(r + 2176 + g * 8);
        float4 C_n1 = *(const float4*)(r + 2176 + g * 8 + 4);
        int idxn = ((b << 10) + ln) * NHEADS + h;
        float dt_n = dtp[idxn], dA_n = dAb[idxn];

        const float c = dt_c * x_c;
        const float* Bp = (const float*)B_c;
        const float* Cp = (const float*)C_c;
        float ysum = 0.f;
#pragma unroll
        for (int j = 0; j < 8; ++j) {
            hs[j] = fmaf(hs[j], dA_c, c * Bp[j]);
            ysum = fmaf(hs[j], Cp[j], ysum);
        }
        ysum += __shfl_xor(ysum, 1);
        ysum += __shfl_xor(ysum, 2);
        ysum += __shfl_xor(ysum, 4);
        ysum += __shfl_xor(ysum, 8);
        if (g == 0)
            yws[((size_t)(b << 10) + l) * D_INNER + h * 64 + p] = ysum + Dh * x_c;

        dt_c = dt_n; dA_c = dA_n; x_c = x_n;
        B_c[0] = B_n0; B_c[1] = B_n1; C_c[0] = C_n0; C_c[1] = C_n1;
    }
}

// ---------------------------------------------------------------------------
// y*silu(z) -> RMSNorm -> *norm_w -> bf16 for out_proj GEMM
// ---------------------------------------------------------------------------
__global__ __launch_bounds__(256)
void gate_norm(const float* __restrict__ yws,
               const __hip_bfloat16* __restrict__ zxb,
               const void* __restrict__ norm_w,
               const int* __restrict__ flagp,
               __hip_bfloat16* __restrict__ yg)
{
    const int isf = *flagp;
    const int row = blockIdx.x;
    const float* y = yws + (size_t)row * D_INNER;
    const __hip_bfloat16* z = zxb + (size_t)row * ZX_STR;
    float v[8]; float ss = 0.f;
#pragma unroll
    for (int it = 0; it < 8; ++it) {
        int c = it * 256 + threadIdx.x;
        float zz = bf2f(z[c]);
        float vv = y[c] * (zz / (1.f + expf(-zz)));
        v[it] = vv;
        ss += vv * vv;
    }
#pragma unroll
    for (int m = 1; m < 64; m <<= 1) ss += __shfl_xor(ss, m);
    __shared__ float red[4];
    if ((threadIdx.x & 63) == 0) red[threadIdx.x >> 6] = ss;
    __syncthreads();
    float tot = red[0] + red[1] + red[2] + red[3];
    float scale = rsqrtf(tot / (float)D_INNER + 1e-5f);
#pragma unroll
    for (int it = 0; it < 8; ++it) {
        int c = it * 256 + threadIdx.x;
        yg[(size_t)row * D_INNER + c] =
            __float2bfloat16(v[it] * scale * rdin(norm_w, c, isf));
    }
}

extern "C" void kernel_launch(void* const* d_in, const int* in_sizes, int n_in,
                              void* d_out, int out_size, void* d_ws, size_t ws_size,
                              hipStream_t stream)
{
    const void* x_raw    = d_in[0];
    const void* inw_raw  = d_in[1];
    const void* convw    = d_in[2];
    const void* convb    = d_in[3];
    const void* dtb      = d_in[4];
    const void* Alog     = d_in[5];
    const void* Dsk      = d_in[6];
    const void* normw    = d_in[7];
    const void* outw_raw = d_in[8];

    char* ws = (char*)d_ws;
    size_t off = 0;
    int* flag = (int*)(ws + off);                      off += 256;
    __hip_bfloat16* xb    = (__hip_bfloat16*)(ws+off); off += (size_t)NROWS * D_MODEL * 2;      // 4.19 MB
    __hip_bfloat16* inwb  = (__hip_bfloat16*)(ws+off); off += (size_t)4384 * D_MODEL * 2;       // 8.98 MB
    __hip_bfloat16* outwb = (__hip_bfloat16*)(ws+off); off += (size_t)D_MODEL * D_INNER * 2;    // 4.19 MB
    __hip_bfloat16* zxb   = (__hip_bfloat16*)(ws+off); off += (size_t)NROWS * ZX_STR * 2;       // 17.8 MB
    float* xBCc = (float*)(ws+off);                    off += (size_t)NROWS * CONV_DIM * 4;     // 18.9 MB
    float* dtp  = (float*)(ws+off);                    off += (size_t)NROWS * NHEADS * 4;
    float* dAb  = (float*)(ws+off);                    off += (size_t)NROWS * NHEADS * 4;
    float* yws  = (float*)(ws+off);                    off += (size_t)NROWS * D_INNER * 4;      // 16.8 MB
    __hip_bfloat16* yg = (__hip_bfloat16*)(ws+off);    off += (size_t)NROWS * D_INNER * 2;      // 8.39 MB

    // 0. dtype vote
    detect_dtype<<<1, 256, 0, stream>>>((const unsigned short*)x_raw, flag);
    // 1. canonical bf16 copies of the GEMM operands
    to_bf16<<<1024, 256, 0, stream>>>(x_raw,    xb,    NROWS * D_MODEL / 8, flag);
    to_bf16<<<2192, 256, 0, stream>>>(inw_raw,  inwb,  4384 * D_MODEL / 8,  flag);
    to_bf16<<<1024, 256, 0, stream>>>(outw_raw, outwb, D_MODEL * D_INNER / 8, flag);
    // 2. in_proj (z + xBC columns only): zxb[2048,4352]
    gemm_bt<0><<<dim3(34, 16), 256, 0, stream>>>(xb, inwb, zxb, nullptr, nullptr,
                                                 flag, D_MODEL, ZX_STR);
    // 3. fp32 dt path from raw inputs
    dt_kernel<<<NROWS, 256, 0, stream>>>(x_raw, inw_raw, dtb, Alog, flag, dtp, dAb);
    // 4. causal depthwise conv + SiLU
    conv_silu<<<NROWS, 256, 0, stream>>>(zxb, convw, convb, flag, xBCc);
    // 5. selective scan
    scan_kernel<<<256, 256, 0, stream>>>(xBCc, dtp, dAb, Dsk, flag, yws);
    // 6. gated RMSNorm -> bf16
    gate_norm<<<NROWS, 256, 0, stream>>>(yws, zxb, normw, flag, yg);
    // 7. out_proj + residual (flag-dtype store)
    gemm_bt<1><<<dim3(8, 16), 256, 0, stream>>>(yg, outwb, nullptr, xb, d_out,
                                                flag, D_INNER, D_MODEL);
}

// Round 3
// 309.404 us; speedup vs baseline: 2.3997x; 2.3997x over previous
//
#include <hip/hip_runtime.h>
#include <hip/hip_bf16.h>
#include <math.h>

#define NHEADS   32
#define CONV_DIM 2304
#define D_INNER  2048
#define SEQLEN   1024
#define NROWS    2048     // BATCH*SEQLEN
#define ZX_STR   4352     // z(2048) + xBC(2304); dt columns handled separately
#define D_MODEL  1024
#define Q        64       // chunk length
#define NCHUNK   16       // SEQLEN / Q
#define XT_STR   72       // LDS transpose row stride (shorts): 144B = 16B-aligned

typedef __attribute__((ext_vector_type(8))) short bhalf8;
typedef __attribute__((ext_vector_type(4))) short short4v;
typedef __attribute__((ext_vector_type(4))) float f32x4;

__device__ __forceinline__ float bf2f(__hip_bfloat16 v){ return __bfloat162float(v); }
__device__ __forceinline__ short f2bs(float f){ __hip_bfloat16 h = __float2bfloat16(f); return *(short*)&h; }
__device__ __forceinline__ float s2f(short s){ __hip_bfloat16 h = *(__hip_bfloat16*)&s; return __bfloat162float(h); }
__device__ __forceinline__ float rdin(const void* p, size_t i, int isf){
    return isf ? ((const float*)p)[i] : __bfloat162float(((const __hip_bfloat16*)p)[i]);
}

// ---------------------------------------------------------------------------
// Dtype detection (fp32 vs bf16 inputs): vote on exponent sanity of even halves.
// ---------------------------------------------------------------------------
__global__ __launch_bounds__(256)
void detect_dtype(const unsigned short* __restrict__ p, int* __restrict__ flag)
{
    int cnt = 0;
    for (int i = threadIdx.x; i < 4096; i += 256) {
        unsigned short u = p[2 * i];
        int e = (u >> 7) & 0xFF;
        cnt += (e >= 90 && e <= 141) ? 1 : 0;
    }
#pragma unroll
    for (int m = 1; m < 64; m <<= 1) cnt += __shfl_xor(cnt, m);
    __shared__ int red[4];
    if ((threadIdx.x & 63) == 0) red[threadIdx.x >> 6] = cnt;
    __syncthreads();
    if (threadIdx.x == 0) *flag = ((red[0]+red[1]+red[2]+red[3]) < 2048) ? 1 : 0;
}

typedef __attribute__((ext_vector_type(8))) short short8;
__global__ __launch_bounds__(256)
void to_bf16(const void* __restrict__ src, __hip_bfloat16* __restrict__ dst,
             int n8, const int* __restrict__ flagp)
{
    const int isf = *flagp;
    int i = blockIdx.x * 256 + threadIdx.x;
    if (i >= n8) return;
    if (isf) {
        const float4* s = (const float4*)src;
        float4 a = s[2 * i], b = s[2 * i + 1];
        short8 r;
        r[0]=f2bs(a.x); r[1]=f2bs(a.y); r[2]=f2bs(a.z); r[3]=f2bs(a.w);
        r[4]=f2bs(b.x); r[5]=f2bs(b.y); r[6]=f2bs(b.z); r[7]=f2bs(b.w);
        ((short8*)dst)[i] = r;
    } else {
        ((float4*)dst)[i] = ((const float4*)src)[i];
    }
}

// ---------------------------------------------------------------------------
// GEMM C[m,n] = sum_k A[m,k]*W[n,k]. MODE 0: bf16 store. MODE 1: +resid,
// flag-dtype store. (unchanged from round 2 — known good)
// ---------------------------------------------------------------------------
template<int MODE>
__global__ __launch_bounds__(256)
void gemm_bt(const __hip_bfloat16* __restrict__ A,
             const __hip_bfloat16* __restrict__ W,
             __hip_bfloat16* __restrict__ Cb,
             const __hip_bfloat16* __restrict__ resid,
             void* __restrict__ outv,
             const int* __restrict__ flagp,
             int K, int N)
{
    __shared__ short As[128 * 64];
    __shared__ short Bs[128 * 64];
    const int m0 = blockIdx.y * 128;
    const int n0 = blockIdx.x * 128;
    const int wave = threadIdx.x >> 6;
    const int lane = threadIdx.x & 63;
    const int lr8 = lane >> 3, lc8 = lane & 7;
    const int lr  = lane & 15, lq  = lane >> 4;
    const int wm = (wave & 1) * 64, wn = (wave >> 1) * 64;

    f32x4 acc[4][4];
#pragma unroll
    for (int i = 0; i < 4; ++i)
#pragma unroll
        for (int j = 0; j < 4; ++j) acc[i][j] = (f32x4){0.f,0.f,0.f,0.f};

    for (int k0 = 0; k0 < K; k0 += 64) {
#pragma unroll
        for (int i = 0; i < 4; ++i) {
            const int rt = wave * 32 + i * 8;
            const __hip_bfloat16* gp = A + (size_t)(m0 + rt + lr8) * K + k0 + lc8 * 8;
            __builtin_amdgcn_global_load_lds(
                (const __attribute__((address_space(1))) void*)gp,
                (__attribute__((address_space(3))) void*)&As[rt * 64], 16, 0, 0);
        }
#pragma unroll
        for (int i = 0; i < 4; ++i) {
            const int rt = wave * 32 + i * 8;
            const __hip_bfloat16* gp = W + (size_t)(n0 + rt + lr8) * K + k0 + lc8 * 8;
            __builtin_amdgcn_global_load_lds(
                (const __attribute__((address_space(1))) void*)gp,
                (__attribute__((address_space(3))) void*)&Bs[rt * 64], 16, 0, 0);
        }
        __syncthreads();
#pragma unroll
        for (int kk = 0; kk < 64; kk += 32) {
            bhalf8 af[4], bfv[4];
#pragma unroll
            for (int t = 0; t < 4; ++t)
                af[t]  = *(const bhalf8*)&As[(wm + t * 16 + lr) * 64 + kk + lq * 8];
#pragma unroll
            for (int t = 0; t < 4; ++t)
                bfv[t] = *(const bhalf8*)&Bs[(wn + t * 16 + lr) * 64 + kk + lq * 8];
#pragma unroll
            for (int ti = 0; ti < 4; ++ti)
#pragma unroll
                for (int tj = 0; tj < 4; ++tj)
                    acc[ti][tj] = __builtin_amdgcn_mfma_f32_16x16x32_bf16(
                        af[ti], bfv[tj], acc[ti][tj], 0, 0, 0);
        }
        __syncthreads();
    }

    const int isf = (MODE == 1) ? *flagp : 0;
#pragma unroll
    for (int ti = 0; ti < 4; ++ti)
#pragma unroll
        for (int tj = 0; tj < 4; ++tj)
#pragma unroll
            for (int r = 0; r < 4; ++r) {
                int m = m0 + wm + ti * 16 + lq * 4 + r;
                int n = n0 + wn + tj * 16 + lr;
                size_t idx = (size_t)m * N + n;
                float v = acc[ti][tj][r];
                if (MODE == 0) {
                    Cb[idx] = __float2bfloat16(v);
                } else {
                    v += bf2f(resid[idx]);
                    if (isf) ((float*)outv)[idx] = v;
                    else     ((__hip_bfloat16*)outv)[idx] = __float2bfloat16(v);
                }
            }
}

// ---------------------------------------------------------------------------
// fp32 dt path from RAW inputs: dtp = softplus(x·W_dt + dt_bias)
// ---------------------------------------------------------------------------
__global__ __launch_bounds__(256)
void dt_kernel(const void* __restrict__ xraw, const void* __restrict__ wraw,
               const void* __restrict__ dt_bias,
               const int* __restrict__ flagp,
               float* __restrict__ dtp)
{
    const int isf = *flagp;
    const int row = blockIdx.x;
    __shared__ float xs[D_MODEL];
    for (int k = threadIdx.x; k < D_MODEL; k += 256)
        xs[k] = rdin(xraw, (size_t)row * D_MODEL + k, isf);
    __syncthreads();
    const int h = threadIdx.x >> 3;
    const int t = threadIdx.x & 7;
    const size_t wbase = (size_t)(4352 + h) * D_MODEL;
    float s = 0.f;
    for (int k = t; k < D_MODEL; k += 8)
        s += xs[k] * rdin(wraw, wbase + k, isf);
    s += __shfl_xor(s, 1);
    s += __shfl_xor(s, 2);
    s += __shfl_xor(s, 4);
    if (t == 0) {
        float raw = s + rdin(dt_bias, h, isf);
        dtp[(size_t)row * NHEADS + h] = raw > 20.f ? raw : log1pf(expf(raw));
    }
}

// ---------------------------------------------------------------------------
// Depthwise causal conv(4) + bias + SiLU -> split bf16 outputs xs/B/C
// ---------------------------------------------------------------------------
__global__ __launch_bounds__(256)
void conv_silu(const __hip_bfloat16* __restrict__ zxb,
               const void* __restrict__ conv_w, const void* __restrict__ conv_b,
               const int* __restrict__ flagp,
               __hip_bfloat16* __restrict__ xs_bf,
               __hip_bfloat16* __restrict__ B_bf,
               __hip_bfloat16* __restrict__ C_bf)
{
    const int isf = *flagp;
    const int row = blockIdx.x;
    const int l = row & (SEQLEN - 1);
    for (int c = threadIdx.x; c < CONV_DIM; c += 256) {
        float acc = rdin(conv_b, c, isf);
#pragma unroll
        for (int j = 0; j < 4; ++j) {
            int ls = l - 3 + j;
            if (ls >= 0)
                acc += bf2f(zxb[(size_t)(row - 3 + j) * ZX_STR + 2048 + c]) *
                       rdin(conv_w, (size_t)c * 4 + j, isf);
        }
        float v = acc / (1.f + expf(-acc));
        __hip_bfloat16 bv = __float2bfloat16(v);
        if (c < 2048)       xs_bf[(size_t)row * 2048 + c] = bv;
        else if (c < 2176)  B_bf[(size_t)row * 128 + (c - 2048)] = bv;
        else                C_bf[(size_t)row * 128 + (c - 2176)] = bv;
    }
}

// ---------------------------------------------------------------------------
// Per-(b,h,chunk) log-decay prefix: cum_t = sum_{r<=t} dtp_r*An;
// u_t = exp(cum_Q - cum_t)*dtp_t; decay = exp(cum_Q). 1024 blocks x 64 thr.
// ---------------------------------------------------------------------------
__global__ __launch_bounds__(64)
void cum_kernel(const float* __restrict__ dtp, const void* __restrict__ Alog,
                const int* __restrict__ flagp,
                float* __restrict__ cumg, float* __restrict__ ug,
                float* __restrict__ decayg)
{
    const int isf = *flagp;
    const int bhc = blockIdx.x;
    const int c = bhc & 15, h = (bhc >> 4) & 31, b = bhc >> 9;
    const int t = threadIdx.x;
    const int row0 = b * SEQLEN + c * Q;
    const float An = -expf(rdin(Alog, h, isf));
    const float dt = dtp[(size_t)(row0 + t) * NHEADS + h];
    float cum = dt * An;
#pragma unroll
    for (int ofs = 1; ofs < 64; ofs <<= 1) {
        float v = __shfl_up(cum, ofs);
        if (t >= ofs) cum += v;
    }
    float tot = __shfl(cum, 63);
    cumg[(size_t)bhc * Q + t] = cum;
    ug[(size_t)bhc * Q + t] = expf(tot - cum) * dt;
    if (t == 63) decayg[bhc] = expf(tot);
}

// ---------------------------------------------------------------------------
// GM kernel: G = C·B^T (64x64, K=128) masked -> M[t,s]=G*exp(cum_t-cum_s)*dt_s
// for s<=t, else 0. Fragments read direct global->registers. 1024 blocks.
// ---------------------------------------------------------------------------
__global__ __launch_bounds__(256)
void gm_kernel(const __hip_bfloat16* __restrict__ B_bf,
               const __hip_bfloat16* __restrict__ C_bf,
               const float* __restrict__ cumg, const float* __restrict__ dtp,
               __hip_bfloat16* __restrict__ M_bf)
{
    const int bhc = blockIdx.x;
    const int c = bhc & 15, h = (bhc >> 4) & 31, b = bhc >> 9;
    const int row0 = b * SEQLEN + c * Q;
    const int wave = threadIdx.x >> 6, lane = threadIdx.x & 63;
    const int lr = lane & 15, lq = lane >> 4;
    const int t0 = wave * 16;

    f32x4 acc[4];
#pragma unroll
    for (int j = 0; j < 4; ++j) acc[j] = (f32x4){0.f,0.f,0.f,0.f};

#pragma unroll
    for (int kk = 0; kk < 128; kk += 32) {
        bhalf8 af = *(const bhalf8*)&C_bf[(size_t)(row0 + t0 + lr) * 128 + kk + lq * 8];
#pragma unroll
        for (int j = 0; j < 4; ++j) {
            bhalf8 bf = *(const bhalf8*)&B_bf[(size_t)(row0 + j * 16 + lr) * 128 + kk + lq * 8];
            acc[j] = __builtin_amdgcn_mfma_f32_16x16x32_bf16(af, bf, acc[j], 0, 0, 0);
        }
    }
    float ct[4], cs[4], dts[4];
#pragma unroll
    for (int r = 0; r < 4; ++r) ct[r] = cumg[(size_t)bhc * Q + t0 + lq * 4 + r];
#pragma unroll
    for (int j = 0; j < 4; ++j) {
        int s = j * 16 + lr;
        cs[j]  = cumg[(size_t)bhc * Q + s];
        dts[j] = dtp[(size_t)(row0 + s) * NHEADS + h];
    }
#pragma unroll
    for (int j = 0; j < 4; ++j)
#pragma unroll
        for (int r = 0; r < 4; ++r) {
            int t = t0 + lq * 4 + r;
            int s = j * 16 + lr;
            float m = (s <= t) ? acc[j][r] * expf(ct[r] - cs[j]) * dts[j] : 0.f;
            M_bf[(size_t)bhc * 4096 + t * 64 + s] = __float2bfloat16(m);
        }
}

// ---------------------------------------------------------------------------
// S kernel: S[p,n] = sum_t u_t*x_t[p]*B_t[n]  (64x128, K=64). X,B transposed
// in LDS (stride 72 shorts). 1024 blocks.
// ---------------------------------------------------------------------------
__global__ __launch_bounds__(256)
void s_kernel(const __hip_bfloat16* __restrict__ xs_bf,
              const __hip_bfloat16* __restrict__ B_bf,
              const float* __restrict__ ug,
              float* __restrict__ S)
{
    __shared__ short Xt[64 * XT_STR];
    __shared__ short Bt[128 * XT_STR];
    const int bhc = blockIdx.x;
    const int c = bhc & 15, h = (bhc >> 4) & 31, b = bhc >> 9;
    const int row0 = b * SEQLEN + c * Q;

    // transpose X (scaled by u_t) : Xt[p][t] = x[t, h*64+p] * u_t
#pragma unroll
    for (int i = 0; i < 2; ++i) {
        int seg = threadIdx.x + i * 256;           // 512 segs of 8
        int t = seg >> 3, p8 = (seg & 7) * 8;
        float ut = ug[(size_t)bhc * Q + t];
        bhalf8 v = *(const bhalf8*)&xs_bf[(size_t)(row0 + t) * 2048 + h * 64 + p8];
#pragma unroll
        for (int j = 0; j < 8; ++j)
            Xt[(p8 + j) * XT_STR + t] = f2bs(s2f(v[j]) * ut);
    }
    // transpose B : Bt[n][t]
#pragma unroll
    for (int i = 0; i < 4; ++i) {
        int seg = threadIdx.x + i * 256;           // 1024 segs of 8
        int t = seg >> 4, n8 = (seg & 15) * 8;
        bhalf8 v = *(const bhalf8*)&B_bf[(size_t)(row0 + t) * 128 + n8];
#pragma unroll
        for (int j = 0; j < 8; ++j)
            Bt[(n8 + j) * XT_STR + t] = v[j];
    }
    __syncthreads();

    const int wave = threadIdx.x >> 6, lane = threadIdx.x & 63;
    const int lr = lane & 15, lq = lane >> 4;
    const int p0 = wave * 16;
    f32x4 acc[8];
#pragma unroll
    for (int j = 0; j < 8; ++j) acc[j] = (f32x4){0.f,0.f,0.f,0.f};
#pragma unroll
    for (int kk = 0; kk < 64; kk += 32) {
        bhalf8 af = *(const bhalf8*)&Xt[(p0 + lr) * XT_STR + kk + lq * 8];
#pragma unroll
        for (int j = 0; j < 8; ++j) {
            bhalf8 bf = *(const bhalf8*)&Bt[(j * 16 + lr) * XT_STR + kk + lq * 8];
            acc[j] = __builtin_amdgcn_mfma_f32_16x16x32_bf16(af, bf, acc[j], 0, 0, 0);
        }
    }
#pragma unroll
    for (int j = 0; j < 8; ++j)
#pragma unroll
        for (int r = 0; r < 4; ++r) {
            int p = p0 + lq * 4 + r;
            int n = j * 16 + lr;
            S[(size_t)bhc * 8192 + p * 128 + n] = acc[j][r];
        }
}

// ---------------------------------------------------------------------------
// Inter-chunk recurrence (16 serial steps, elementwise in p,n):
// hstart(c) = h; h = decay(c)*h + S_c.  512 blocks x 256 thr x 4 elems.
// ---------------------------------------------------------------------------
__global__ __launch_bounds__(256)
void rec_kernel(const float* __restrict__ S, const float* __restrict__ decayg,
                __hip_bfloat16* __restrict__ hst)
{
    const int bh = blockIdx.x >> 3;
    const int sl = blockIdx.x & 7;
    const int off = sl * 1024 + threadIdx.x * 4;
    float h0 = 0.f, h1 = 0.f, h2 = 0.f, h3 = 0.f;
    for (int c = 0; c < NCHUNK; ++c) {
        size_t base = ((size_t)bh * NCHUNK + c) * 8192 + off;
        short4v hb;
        hb[0] = f2bs(h0); hb[1] = f2bs(h1); hb[2] = f2bs(h2); hb[3] = f2bs(h3);
        *(short4v*)&hst[base] = hb;
        float4 s = *(const float4*)&S[base];
        float d = decayg[bh * NCHUNK + c];
        h0 = fmaf(h0, d, s.x); h1 = fmaf(h1, d, s.y);
        h2 = fmaf(h2, d, s.z); h3 = fmaf(h3, d, s.w);
    }
}

// ---------------------------------------------------------------------------
// Y kernel: Y[t,p] = (M·X)[t,p] + exp(cum_t)*(C·hstart^T)[t,p] + Dh*x[t,p]
// -> yws fp32 [row, h*64+p]. 1024 blocks.
// ---------------------------------------------------------------------------
__global__ __launch_bounds__(256)
void y_kernel(const __hip_bfloat16* __restrict__ M_bf,
              const __hip_bfloat16* __restrict__ xs_bf,
              const __hip_bfloat16* __restrict__ C_bf,
              const __hip_bfloat16* __restrict__ hst,
              const float* __restrict__ cumg,
              const void* __restrict__ Draw, const int* __restrict__ flagp,
              float* __restrict__ yws)
{
    __shared__ short Xt[64 * XT_STR];
    const int bhc = blockIdx.x;
    const int c = bhc & 15, h = (bhc >> 4) & 31, b = bhc >> 9;
    const int row0 = b * SEQLEN + c * Q;
    const int isf = *flagp;
    const float Dh = rdin(Draw, h, isf);

    // transpose X: Xt[p][t] = x[t, h*64+p]
#pragma unroll
    for (int i = 0; i < 2; ++i) {
        int seg = threadIdx.x + i * 256;
        int t = seg >> 3, p8 = (seg & 7) * 8;
        bhalf8 v = *(const bhalf8*)&xs_bf[(size_t)(row0 + t) * 2048 + h * 64 + p8];
#pragma unroll
        for (int j = 0; j < 8; ++j)
            Xt[(p8 + j) * XT_STR + t] = v[j];
    }
    __syncthreads();

    const int wave = threadIdx.x >> 6, lane = threadIdx.x & 63;
    const int lr = lane & 15, lq = lane >> 4;
    const int t0 = wave * 16;
    f32x4 acc1[4], acc2[4];
#pragma unroll
    for (int j = 0; j < 4; ++j) { acc1[j] = (f32x4){0.f,0.f,0.f,0.f}; acc2[j] = acc1[j]; }

    // part 1: M·X  (K = s = 64)
#pragma unroll
    for (int kk = 0; kk < 64; kk += 32) {
        bhalf8 af = *(const bhalf8*)&M_bf[(size_t)bhc * 4096 + (t0 + lr) * 64 + kk + lq * 8];
#pragma unroll
        for (int j = 0; j < 4; ++j) {
            bhalf8 bf = *(const bhalf8*)&Xt[(j * 16 + lr) * XT_STR + kk + lq * 8];
            acc1[j] = __builtin_amdgcn_mfma_f32_16x16x32_bf16(af, bf, acc1[j], 0, 0, 0);
        }
    }
    // part 2: C·hstart^T (K = n = 128)
#pragma unroll
    for (int kk = 0; kk < 128; kk += 32) {
        bhalf8 af = *(const bhalf8*)&C_bf[(size_t)(row0 + t0 + lr) * 128 + kk + lq * 8];
#pragma unroll
        for (int j = 0; j < 4; ++j) {
            bhalf8 bf = *(const bhalf8*)&hst[(size_t)bhc * 8192 + (j * 16 + lr) * 128 + kk + lq * 8];
            acc2[j] = __builtin_amdgcn_mfma_f32_16x16x32_bf16(af, bf, acc2[j], 0, 0, 0);
        }
    }
    float ex[4];
#pragma unroll
    for (int r = 0; r < 4; ++r) ex[r] = expf(cumg[(size_t)bhc * Q + t0 + lq * 4 + r]);
#pragma unroll
    for (int j = 0; j < 4; ++j)
#pragma unroll
        for (int r = 0; r < 4; ++r) {
            int t = t0 + lq * 4 + r;
            int p = j * 16 + lr;
            float xv = s2f(Xt[p * XT_STR + t]);
            float y = acc1[j][r] + ex[r] * acc2[j][r] + Dh * xv;
            yws[(size_t)(row0 + t) * D_INNER + h * 64 + p] = y;
        }
}

// ---------------------------------------------------------------------------
// y*silu(z) -> RMSNorm -> *norm_w -> bf16
// ---------------------------------------------------------------------------
__global__ __launch_bounds__(256)
void gate_norm(const float* __restrict__ yws,
               const __hip_bfloat16* __restrict__ zxb,
               const void* __restrict__ norm_w,
               const int* __restrict__ flagp,
               __hip_bfloat16* __restrict__ yg)
{
    const int isf = *flagp;
    const int row = blockIdx.x;
    const float* y = yws + (size_t)row * D_INNER;
    const __hip_bfloat16* z = zxb + (size_t)row * ZX_STR;
    float v[8]; float ss = 0.f;
#pragma unroll
    for (int it = 0; it < 8; ++it) {
        int c = it * 256 + threadIdx.x;
        float zz = bf2f(z[c]);
        float vv = y[c] * (zz / (1.f + expf(-zz)));
        v[it] = vv;
        ss += vv * vv;
    }
#pragma unroll
    for (int m = 1; m < 64; m <<= 1) ss += __shfl_xor(ss, m);
    __shared__ float red[4];
    if ((threadIdx.x & 63) == 0) red[threadIdx.x >> 6] = ss;
    __syncthreads();
    float tot = red[0] + red[1] + red[2] + red[3];
    float scale = rsqrtf(tot / (float)D_INNER + 1e-5f);
#pragma unroll
    for (int it = 0; it < 8; ++it) {
        int c = it * 256 + threadIdx.x;
        yg[(size_t)row * D_INNER + c] =
            __float2bfloat16(v[it] * scale * rdin(norm_w, c, isf));
    }
}

extern "C" void kernel_launch(void* const* d_in, const int* in_sizes, int n_in,
                              void* d_out, int out_size, void* d_ws, size_t ws_size,
                              hipStream_t stream)
{
    const void* x_raw    = d_in[0];
    const void* inw_raw  = d_in[1];
    const void* convw    = d_in[2];
    const void* convb    = d_in[3];
    const void* dtb      = d_in[4];
    const void* Alog     = d_in[5];
    const void* Dsk      = d_in[6];
    const void* normw    = d_in[7];
    const void* outw_raw = d_in[8];

    char* ws = (char*)d_ws;
    size_t off = 0;
    int* flag = (int*)(ws + off);                      off += 256;
    __hip_bfloat16* xb    = (__hip_bfloat16*)(ws+off); off += (size_t)NROWS * D_MODEL * 2;   // 4.2 MB
    __hip_bfloat16* inwb  = (__hip_bfloat16*)(ws+off); off += (size_t)4384 * D_MODEL * 2;    // 9.0 MB
    __hip_bfloat16* outwb = (__hip_bfloat16*)(ws+off); off += (size_t)D_MODEL * D_INNER * 2; // 4.2 MB
    __hip_bfloat16* zxb   = (__hip_bfloat16*)(ws+off); off += (size_t)NROWS * ZX_STR * 2;    // 17.8 MB
    __hip_bfloat16* xs_bf = (__hip_bfloat16*)(ws+off); off += (size_t)NROWS * 2048 * 2;      // 8.4 MB
    __hip_bfloat16* B_bf  = (__hip_bfloat16*)(ws+off); off += (size_t)NROWS * 128 * 2;       // 0.5 MB
    __hip_bfloat16* C_bf  = (__hip_bfloat16*)(ws+off); off += (size_t)NROWS * 128 * 2;       // 0.5 MB
    float* dtp   = (float*)(ws+off);                   off += (size_t)NROWS * NHEADS * 4;
    float* cumg  = (float*)(ws+off);                   off += (size_t)1024 * Q * 4;
    float* ug    = (float*)(ws+off);                   off += (size_t)1024 * Q * 4;
    float* decayg= (float*)(ws+off);                   off += (size_t)1024 * 4;
    __hip_bfloat16* M_bf  = (__hip_bfloat16*)(ws+off); off += (size_t)1024 * 4096 * 2;       // 8.4 MB
    __hip_bfloat16* hst   = (__hip_bfloat16*)(ws+off); off += (size_t)1024 * 8192 * 2;       // 16.8 MB
    float* S = (float*)(ws+off);                       off += (size_t)1024 * 8192 * 4;       // 33.6 MB
    // yws/yg alias S's block: S is dead after rec_kernel, before y_kernel writes
    float* yws = S;                                                                          // 16.8 MB
    __hip_bfloat16* yg = (__hip_bfloat16*)(S + (size_t)NROWS * D_INNER);                     // 8.4 MB

    detect_dtype<<<1, 256, 0, stream>>>((const unsigned short*)x_raw, flag);
    to_bf16<<<1024, 256, 0, stream>>>(x_raw,    xb,    NROWS * D_MODEL / 8, flag);
    to_bf16<<<2192, 256, 0, stream>>>(inw_raw,  inwb,  4384 * D_MODEL / 8,  flag);
    to_bf16<<<1024, 256, 0, stream>>>(outw_raw, outwb, D_MODEL * D_INNER / 8, flag);
    // in_proj (z + xBC cols): zxb[2048,4352]
    gemm_bt<0><<<dim3(34, 16), 256, 0, stream>>>(xb, inwb, zxb, nullptr, nullptr,
                                                 flag, D_MODEL, ZX_STR);
    dt_kernel<<<NROWS, 256, 0, stream>>>(x_raw, inw_raw, dtb, flag, dtp);
    conv_silu<<<NROWS, 256, 0, stream>>>(zxb, convw, convb, flag, xs_bf, B_bf, C_bf);
    cum_kernel<<<1024, 64, 0, stream>>>(dtp, Alog, flag, cumg, ug, decayg);
    gm_kernel<<<1024, 256, 0, stream>>>(B_bf, C_bf, cumg, dtp, M_bf);
    s_kernel<<<1024, 256, 0, stream>>>(xs_bf, B_bf, ug, S);
    rec_kernel<<<512, 256, 0, stream>>>(S, decayg, hst);
    y_kernel<<<1024, 256, 0, stream>>>(M_bf, xs_bf, C_bf, hst, cumg, Dsk, flag, yws);
    gate_norm<<<NROWS, 256, 0, stream>>>(yws, zxb, normw, flag, yg);
    gemm_bt<1><<<dim3(8, 16), 256, 0, stream>>>(yg, outwb, nullptr, xb, d_out,
                                                flag, D_INNER, D_MODEL);
}

// Round 4
// 265.311 us; speedup vs baseline: 2.7986x; 1.1662x over previous
//
#include <hip/hip_runtime.h>
#include <hip/hip_bf16.h>
#include <math.h>

#define NHEADS   32
#define CONV_DIM 2304
#define D_INNER  2048
#define SEQLEN   1024
#define NROWS    2048     // BATCH*SEQLEN
#define ZX_STR   4352     // z(2048) + xBC(2304); dt columns handled separately
#define D_MODEL  1024
#define Q        64       // chunk length
#define NCHUNK   16       // SEQLEN / Q
#define XT_STR   72       // LDS transpose row stride (shorts): 144B = 16B-aligned

typedef __attribute__((ext_vector_type(8))) short bhalf8;
typedef __attribute__((ext_vector_type(8))) short short8;
typedef __attribute__((ext_vector_type(4))) short short4v;
typedef __attribute__((ext_vector_type(4))) float f32x4;

__device__ __forceinline__ float bf2f(__hip_bfloat16 v){ return __bfloat162float(v); }
__device__ __forceinline__ short f2bs(float f){ __hip_bfloat16 h = __float2bfloat16(f); return *(short*)&h; }
__device__ __forceinline__ float s2f(short s){ __hip_bfloat16 h = *(__hip_bfloat16*)&s; return __bfloat162float(h); }
__device__ __forceinline__ float rdin(const void* p, size_t i, int isf){
    return isf ? ((const float*)p)[i] : __bfloat162float(((const __hip_bfloat16*)p)[i]);
}

// ---------------------------------------------------------------------------
// Dtype detection (fp32 vs bf16 inputs): vote on exponent sanity of even halves.
// ---------------------------------------------------------------------------
__global__ __launch_bounds__(256)
void detect_dtype(const unsigned short* __restrict__ p, int* __restrict__ flag)
{
    int cnt = 0;
    for (int i = threadIdx.x; i < 4096; i += 256) {
        unsigned short u = p[2 * i];
        int e = (u >> 7) & 0xFF;
        cnt += (e >= 90 && e <= 141) ? 1 : 0;
    }
#pragma unroll
    for (int m = 1; m < 64; m <<= 1) cnt += __shfl_xor(cnt, m);
    __shared__ int red[4];
    if ((threadIdx.x & 63) == 0) red[threadIdx.x >> 6] = cnt;
    __syncthreads();
    if (threadIdx.x == 0) *flag = ((red[0]+red[1]+red[2]+red[3]) < 2048) ? 1 : 0;
}

// ---------------------------------------------------------------------------
// One fused normalize pass for x / in_proj_w / out_proj_w -> canonical bf16.
// ---------------------------------------------------------------------------
#define XN8 262144   // 2048*1024/8
#define WN8 561152   // 4384*1024/8
#define ON8 262144   // 2048*1024/8
__global__ __launch_bounds__(256)
void to_bf16_all(const void* __restrict__ xs, const void* __restrict__ ws,
                 const void* __restrict__ os,
                 __hip_bfloat16* __restrict__ xd, __hip_bfloat16* __restrict__ wd,
                 __hip_bfloat16* __restrict__ od, const int* __restrict__ flagp)
{
    const int isf = *flagp;
    int i = blockIdx.x * 256 + threadIdx.x;
    const void* src; __hip_bfloat16* dst; int j;
    if (i < XN8)            { src = xs; dst = xd; j = i; }
    else if (i < XN8 + WN8) { src = ws; dst = wd; j = i - XN8; }
    else                    { src = os; dst = od; j = i - XN8 - WN8; }
    if (isf) {
        const float4* s = (const float4*)src;
        float4 a = s[2 * j], b = s[2 * j + 1];
        short8 r;
        r[0]=f2bs(a.x); r[1]=f2bs(a.y); r[2]=f2bs(a.z); r[3]=f2bs(a.w);
        r[4]=f2bs(b.x); r[5]=f2bs(b.y); r[6]=f2bs(b.z); r[7]=f2bs(b.w);
        ((short8*)dst)[j] = r;
    } else {
        ((float4*)dst)[j] = ((const float4*)src)[j];
    }
}

// ---------------------------------------------------------------------------
// GEMM C[m,n] = sum_k A[m,k]*W[n,k]. Templated tile MTxNT, 4 waves arranged
// WROWS x WCOLS. MODE 0: bf16 store. MODE 1: + raw-x residual, flag store.
// MT=64 tiles -> 2-4x more blocks than round 3 => latency hidden by occupancy.
// ---------------------------------------------------------------------------
template<int MODE, int MT, int NT, int WROWS, int WCOLS>
__global__ __launch_bounds__(256)
void gemm_bt(const __hip_bfloat16* __restrict__ A,
             const __hip_bfloat16* __restrict__ W,
             __hip_bfloat16* __restrict__ Cb,
             const void* __restrict__ xraw,
             void* __restrict__ outv,
             const int* __restrict__ flagp,
             int K, int N)
{
    constexpr int FM = MT / WROWS / 16;
    constexpr int FN = NT / WCOLS / 16;
    constexpr int AI = MT / 32;          // A-staging instrs per wave
    constexpr int BI = NT / 32;          // B-staging instrs per wave
    __shared__ short As[MT * 64];
    __shared__ short Bs[NT * 64];
    const int m0 = blockIdx.y * MT;
    const int n0 = blockIdx.x * NT;
    const int wave = threadIdx.x >> 6;
    const int lane = threadIdx.x & 63;
    const int lr8 = lane >> 3, lc8 = lane & 7;
    const int lr  = lane & 15, lq  = lane >> 4;
    const int wm = (wave / WCOLS) * (MT / WROWS);
    const int wn = (wave % WCOLS) * (NT / WCOLS);

    f32x4 acc[FM][FN];
#pragma unroll
    for (int i = 0; i < FM; ++i)
#pragma unroll
        for (int j = 0; j < FN; ++j) acc[i][j] = (f32x4){0.f,0.f,0.f,0.f};

    for (int k0 = 0; k0 < K; k0 += 64) {
#pragma unroll
        for (int i = 0; i < AI; ++i) {
            const int rt = (wave * AI + i) * 8;
            const __hip_bfloat16* gp = A + (size_t)(m0 + rt + lr8) * K + k0 + lc8 * 8;
            __builtin_amdgcn_global_load_lds(
                (const __attribute__((address_space(1))) void*)gp,
                (__attribute__((address_space(3))) void*)&As[rt * 64], 16, 0, 0);
        }
#pragma unroll
        for (int i = 0; i < BI; ++i) {
            const int rt = (wave * BI + i) * 8;
            const __hip_bfloat16* gp = W + (size_t)(n0 + rt + lr8) * K + k0 + lc8 * 8;
            __builtin_amdgcn_global_load_lds(
                (const __attribute__((address_space(1))) void*)gp,
                (__attribute__((address_space(3))) void*)&Bs[rt * 64], 16, 0, 0);
        }
        __syncthreads();
#pragma unroll
        for (int kk = 0; kk < 64; kk += 32) {
            bhalf8 af[FM], bfv[FN];
#pragma unroll
            for (int t = 0; t < FM; ++t)
                af[t]  = *(const bhalf8*)&As[(wm + t * 16 + lr) * 64 + kk + lq * 8];
#pragma unroll
            for (int t = 0; t < FN; ++t)
                bfv[t] = *(const bhalf8*)&Bs[(wn + t * 16 + lr) * 64 + kk + lq * 8];
#pragma unroll
            for (int ti = 0; ti < FM; ++ti)
#pragma unroll
                for (int tj = 0; tj < FN; ++tj)
                    acc[ti][tj] = __builtin_amdgcn_mfma_f32_16x16x32_bf16(
                        af[ti], bfv[tj], acc[ti][tj], 0, 0, 0);
        }
        __syncthreads();
    }

    const int isf = (MODE == 1) ? *flagp : 0;
#pragma unroll
    for (int ti = 0; ti < FM; ++ti)
#pragma unroll
        for (int tj = 0; tj < FN; ++tj)
#pragma unroll
            for (int r = 0; r < 4; ++r) {
                int m = m0 + wm + ti * 16 + lq * 4 + r;
                int n = n0 + wn + tj * 16 + lr;
                size_t idx = (size_t)m * N + n;
                float v = acc[ti][tj][r];
                if (MODE == 0) {
                    Cb[idx] = __float2bfloat16(v);
                } else {
                    v += rdin(xraw, idx, isf);     // residual from RAW x
                    if (isf) ((float*)outv)[idx] = v;
                    else     ((__hip_bfloat16*)outv)[idx] = __float2bfloat16(v);
                }
            }
}

// ---------------------------------------------------------------------------
// fp32 dt path from RAW inputs: dtp = softplus(x·W_dt + dt_bias)
// ---------------------------------------------------------------------------
__global__ __launch_bounds__(256)
void dt_kernel(const void* __restrict__ xraw, const void* __restrict__ wraw,
               const void* __restrict__ dt_bias,
               const int* __restrict__ flagp,
               float* __restrict__ dtp)
{
    const int isf = *flagp;
    const int row = blockIdx.x;
    __shared__ float xs[D_MODEL];
    for (int k = threadIdx.x; k < D_MODEL; k += 256)
        xs[k] = rdin(xraw, (size_t)row * D_MODEL + k, isf);
    __syncthreads();
    const int h = threadIdx.x >> 3;
    const int t = threadIdx.x & 7;
    const size_t wbase = (size_t)(4352 + h) * D_MODEL;
    float s = 0.f;
    for (int k = t; k < D_MODEL; k += 8)
        s += xs[k] * rdin(wraw, wbase + k, isf);
    s += __shfl_xor(s, 1);
    s += __shfl_xor(s, 2);
    s += __shfl_xor(s, 4);
    if (t == 0) {
        float raw = s + rdin(dt_bias, h, isf);
        dtp[(size_t)row * NHEADS + h] = raw > 20.f ? raw : log1pf(expf(raw));
    }
}

// ---------------------------------------------------------------------------
// Depthwise causal conv(4) + bias + SiLU -> split bf16 outputs xs/B/C
// ---------------------------------------------------------------------------
__global__ __launch_bounds__(256)
void conv_silu(const __hip_bfloat16* __restrict__ zxb,
               const void* __restrict__ conv_w, const void* __restrict__ conv_b,
               const int* __restrict__ flagp,
               __hip_bfloat16* __restrict__ xs_bf,
               __hip_bfloat16* __restrict__ B_bf,
               __hip_bfloat16* __restrict__ C_bf)
{
    const int isf = *flagp;
    const int row = blockIdx.x;
    const int l = row & (SEQLEN - 1);
    for (int c = threadIdx.x; c < CONV_DIM; c += 256) {
        float acc = rdin(conv_b, c, isf);
#pragma unroll
        for (int j = 0; j < 4; ++j) {
            int ls = l - 3 + j;
            if (ls >= 0)
                acc += bf2f(zxb[(size_t)(row - 3 + j) * ZX_STR + 2048 + c]) *
                       rdin(conv_w, (size_t)c * 4 + j, isf);
        }
        float v = acc / (1.f + expf(-acc));
        __hip_bfloat16 bv = __float2bfloat16(v);
        if (c < 2048)       xs_bf[(size_t)row * 2048 + c] = bv;
        else if (c < 2176)  B_bf[(size_t)row * 128 + (c - 2048)] = bv;
        else                C_bf[(size_t)row * 128 + (c - 2176)] = bv;
    }
}

// ---------------------------------------------------------------------------
// FUSED per-(b,h,chunk) kernel: [cum scan] + [GM: masked C·B^T] + [S: u-scaled
// X^T·B]. Grid 1024 blocks x 256 thr. cum/u/dt live in LDS between phases.
// ---------------------------------------------------------------------------
__global__ __launch_bounds__(256)
void chunk_kernel(const __hip_bfloat16* __restrict__ xs_bf,
                  const __hip_bfloat16* __restrict__ B_bf,
                  const __hip_bfloat16* __restrict__ C_bf,
                  const float* __restrict__ dtp, const void* __restrict__ Alog,
                  const int* __restrict__ flagp,
                  float* __restrict__ cumg, float* __restrict__ decayg,
                  __hip_bfloat16* __restrict__ M_bf, float* __restrict__ S)
{
    __shared__ float cumS[Q], uS[Q], dtS[Q];
    __shared__ short Xt[64 * XT_STR];
    __shared__ short Bt[128 * XT_STR];
    const int bhc = blockIdx.x;
    const int c = bhc & 15, h = (bhc >> 4) & 31, b = bhc >> 9;
    const int row0 = b * SEQLEN + c * Q;
    const int isf = *flagp;

    // ---- phase 0: log-decay prefix scan (wave 0 only) ----
    if (threadIdx.x < 64) {
        const int t = threadIdx.x;
        const float An = -expf(rdin(Alog, h, isf));
        const float dt = dtp[(size_t)(row0 + t) * NHEADS + h];
        float cum = dt * An;
#pragma unroll
        for (int ofs = 1; ofs < 64; ofs <<= 1) {
            float v = __shfl_up(cum, ofs);
            if (t >= ofs) cum += v;
        }
        float tot = __shfl(cum, 63);
        cumS[t] = cum; dtS[t] = dt;
        uS[t] = expf(tot - cum) * dt;
        cumg[(size_t)bhc * Q + t] = cum;          // y_kernel input
        if (t == 63) decayg[bhc] = expf(tot);     // rec_kernel input
    }
    __syncthreads();

    // ---- transposes into LDS (overlap with GM's global loads) ----
#pragma unroll
    for (int i = 0; i < 2; ++i) {
        int seg = threadIdx.x + i * 256;          // 512 segs of 8
        int t = seg >> 3, p8 = (seg & 7) * 8;
        float ut = uS[t];
        bhalf8 v = *(const bhalf8*)&xs_bf[(size_t)(row0 + t) * 2048 + h * 64 + p8];
#pragma unroll
        for (int j = 0; j < 8; ++j)
            Xt[(p8 + j) * XT_STR + t] = f2bs(s2f(v[j]) * ut);
    }
#pragma unroll
    for (int i = 0; i < 4; ++i) {
        int seg = threadIdx.x + i * 256;          // 1024 segs of 8
        int t = seg >> 4, n8 = (seg & 15) * 8;
        bhalf8 v = *(const bhalf8*)&B_bf[(size_t)(row0 + t) * 128 + n8];
#pragma unroll
        for (int j = 0; j < 8; ++j)
            Bt[(n8 + j) * XT_STR + t] = v[j];
    }

    const int wave = threadIdx.x >> 6, lane = threadIdx.x & 63;
    const int lr = lane & 15, lq = lane >> 4;

    // ---- GM phase: G = C·B^T (64x64, K=128), masked-decay -> M_bf ----
    {
        const int t0 = wave * 16;
        f32x4 acc[4];
#pragma unroll
        for (int j = 0; j < 4; ++j) acc[j] = (f32x4){0.f,0.f,0.f,0.f};
#pragma unroll
        for (int kk = 0; kk < 128; kk += 32) {
            bhalf8 af = *(const bhalf8*)&C_bf[(size_t)(row0 + t0 + lr) * 128 + kk + lq * 8];
#pragma unroll
            for (int j = 0; j < 4; ++j) {
                bhalf8 bf = *(const bhalf8*)&B_bf[(size_t)(row0 + j * 16 + lr) * 128 + kk + lq * 8];
                acc[j] = __builtin_amdgcn_mfma_f32_16x16x32_bf16(af, bf, acc[j], 0, 0, 0);
            }
        }
#pragma unroll
        for (int j = 0; j < 4; ++j)
#pragma unroll
            for (int r = 0; r < 4; ++r) {
                int t = t0 + lq * 4 + r;
                int s = j * 16 + lr;
                float m = (s <= t) ? acc[j][r] * expf(cumS[t] - cumS[s]) * dtS[s] : 0.f;
                M_bf[(size_t)bhc * 4096 + t * 64 + s] = __float2bfloat16(m);
            }
    }
    __syncthreads();

    // ---- S phase: S[p,n] = sum_t (u_t x_t[p]) B_t[n]  (64x128, K=64) ----
    {
        const int p0 = wave * 16;
        f32x4 acc[8];
#pragma unroll
        for (int j = 0; j < 8; ++j) acc[j] = (f32x4){0.f,0.f,0.f,0.f};
#pragma unroll
        for (int kk = 0; kk < 64; kk += 32) {
            bhalf8 af = *(const bhalf8*)&Xt[(p0 + lr) * XT_STR + kk + lq * 8];
#pragma unroll
            for (int j = 0; j < 8; ++j) {
                bhalf8 bf = *(const bhalf8*)&Bt[(j * 16 + lr) * XT_STR + kk + lq * 8];
                acc[j] = __builtin_amdgcn_mfma_f32_16x16x32_bf16(af, bf, acc[j], 0, 0, 0);
            }
        }
#pragma unroll
        for (int j = 0; j < 8; ++j)
#pragma unroll
            for (int r = 0; r < 4; ++r) {
                int p = p0 + lq * 4 + r;
                int n = j * 16 + lr;
                S[(size_t)bhc * 8192 + p * 128 + n] = acc[j][r];
            }
    }
}

// ---------------------------------------------------------------------------
// Inter-chunk recurrence (16 serial steps): hstart(c)=h; h = decay*h + S_c.
// ---------------------------------------------------------------------------
__global__ __launch_bounds__(256)
void rec_kernel(const float* __restrict__ S, const float* __restrict__ decayg,
                __hip_bfloat16* __restrict__ hst)
{
    const int bh = blockIdx.x >> 3;
    const int sl = blockIdx.x & 7;
    const int off = sl * 1024 + threadIdx.x * 4;
    float h0 = 0.f, h1 = 0.f, h2 = 0.f, h3 = 0.f;
    for (int c = 0; c < NCHUNK; ++c) {
        size_t base = ((size_t)bh * NCHUNK + c) * 8192 + off;
        short4v hb;
        hb[0] = f2bs(h0); hb[1] = f2bs(h1); hb[2] = f2bs(h2); hb[3] = f2bs(h3);
        *(short4v*)&hst[base] = hb;
        float4 s = *(const float4*)&S[base];
        float d = decayg[bh * NCHUNK + c];
        h0 = fmaf(h0, d, s.x); h1 = fmaf(h1, d, s.y);
        h2 = fmaf(h2, d, s.z); h3 = fmaf(h3, d, s.w);
    }
}

// ---------------------------------------------------------------------------
// Y kernel: Y[t,p] = (M·X)[t,p] + exp(cum_t)*(C·hstart^T)[t,p] + Dh*x[t,p]
// ---------------------------------------------------------------------------
__global__ __launch_bounds__(256)
void y_kernel(const __hip_bfloat16* __restrict__ M_bf,
              const __hip_bfloat16* __restrict__ xs_bf,
              const __hip_bfloat16* __restrict__ C_bf,
              const __hip_bfloat16* __restrict__ hst,
              const float* __restrict__ cumg,
              const void* __restrict__ Draw, const int* __restrict__ flagp,
              float* __restrict__ yws)
{
    __shared__ short Xt[64 * XT_STR];
    const int bhc = blockIdx.x;
    const int c = bhc & 15, h = (bhc >> 4) & 31, b = bhc >> 9;
    const int row0 = b * SEQLEN + c * Q;
    const int isf = *flagp;
    const float Dh = rdin(Draw, h, isf);

#pragma unroll
    for (int i = 0; i < 2; ++i) {
        int seg = threadIdx.x + i * 256;
        int t = seg >> 3, p8 = (seg & 7) * 8;
        bhalf8 v = *(const bhalf8*)&xs_bf[(size_t)(row0 + t) * 2048 + h * 64 + p8];
#pragma unroll
        for (int j = 0; j < 8; ++j)
            Xt[(p8 + j) * XT_STR + t] = v[j];
    }
    __syncthreads();

    const int wave = threadIdx.x >> 6, lane = threadIdx.x & 63;
    const int lr = lane & 15, lq = lane >> 4;
    const int t0 = wave * 16;
    f32x4 acc1[4], acc2[4];
#pragma unroll
    for (int j = 0; j < 4; ++j) { acc1[j] = (f32x4){0.f,0.f,0.f,0.f}; acc2[j] = acc1[j]; }

#pragma unroll
    for (int kk = 0; kk < 64; kk += 32) {
        bhalf8 af = *(const bhalf8*)&M_bf[(size_t)bhc * 4096 + (t0 + lr) * 64 + kk + lq * 8];
#pragma unroll
        for (int j = 0; j < 4; ++j) {
            bhalf8 bf = *(const bhalf8*)&Xt[(j * 16 + lr) * XT_STR + kk + lq * 8];
            acc1[j] = __builtin_amdgcn_mfma_f32_16x16x32_bf16(af, bf, acc1[j], 0, 0, 0);
        }
    }
#pragma unroll
    for (int kk = 0; kk < 128; kk += 32) {
        bhalf8 af = *(const bhalf8*)&C_bf[(size_t)(row0 + t0 + lr) * 128 + kk + lq * 8];
#pragma unroll
        for (int j = 0; j < 4; ++j) {
            bhalf8 bf = *(const bhalf8*)&hst[(size_t)bhc * 8192 + (j * 16 + lr) * 128 + kk + lq * 8];
            acc2[j] = __builtin_amdgcn_mfma_f32_16x16x32_bf16(af, bf, acc2[j], 0, 0, 0);
        }
    }
    float ex[4];
#pragma unroll
    for (int r = 0; r < 4; ++r) ex[r] = expf(cumg[(size_t)bhc * Q + t0 + lq * 4 + r]);
#pragma unroll
    for (int j = 0; j < 4; ++j)
#pragma unroll
        for (int r = 0; r < 4; ++r) {
            int t = t0 + lq * 4 + r;
            int p = j * 16 + lr;
            float xv = s2f(Xt[p * XT_STR + t]);
            float y = acc1[j][r] + ex[r] * acc2[j][r] + Dh * xv;
            yws[(size_t)(row0 + t) * D_INNER + h * 64 + p] = y;
        }
}

// ---------------------------------------------------------------------------
// y*silu(z) -> RMSNorm -> *norm_w -> bf16
// ---------------------------------------------------------------------------
__global__ __launch_bounds__(256)
void gate_norm(const float* __restrict__ yws,
               const __hip_bfloat16* __restrict__ zxb,
               const void* __restrict__ norm_w,
               const int* __restrict__ flagp,
               __hip_bfloat16* __restrict__ yg)
{
    const int isf = *flagp;
    const int row = blockIdx.x;
    const float* y = yws + (size_t)row * D_INNER;
    const __hip_bfloat16* z = zxb + (size_t)row * ZX_STR;
    float v[8]; float ss = 0.f;
#pragma unroll
    for (int it = 0; it < 8; ++it) {
        int c = it * 256 + threadIdx.x;
        float zz = bf2f(z[c]);
        float vv = y[c] * (zz / (1.f + expf(-zz)));
        v[it] = vv;
        ss += vv * vv;
    }
#pragma unroll
    for (int m = 1; m < 64; m <<= 1) ss += __shfl_xor(ss, m);
    __shared__ float red[4];
    if ((threadIdx.x & 63) == 0) red[threadIdx.x >> 6] = ss;
    __syncthreads();
    float tot = red[0] + red[1] + red[2] + red[3];
    float scale = rsqrtf(tot / (float)D_INNER + 1e-5f);
#pragma unroll
    for (int it = 0; it < 8; ++it) {
        int c = it * 256 + threadIdx.x;
        yg[(size_t)row * D_INNER + c] =
            __float2bfloat16(v[it] * scale * rdin(norm_w, c, isf));
    }
}

extern "C" void kernel_launch(void* const* d_in, const int* in_sizes, int n_in,
                              void* d_out, int out_size, void* d_ws, size_t ws_size,
                              hipStream_t stream)
{
    const void* x_raw    = d_in[0];
    const void* inw_raw  = d_in[1];
    const void* convw    = d_in[2];
    const void* convb    = d_in[3];
    const void* dtb      = d_in[4];
    const void* Alog     = d_in[5];
    const void* Dsk      = d_in[6];
    const void* normw    = d_in[7];
    const void* outw_raw = d_in[8];

    char* ws = (char*)d_ws;
    size_t off = 0;
    int* flag = (int*)(ws + off);                      off += 256;
    __hip_bfloat16* xb    = (__hip_bfloat16*)(ws+off); off += (size_t)NROWS * D_MODEL * 2;
    __hip_bfloat16* inwb  = (__hip_bfloat16*)(ws+off); off += (size_t)4384 * D_MODEL * 2;
    __hip_bfloat16* outwb = (__hip_bfloat16*)(ws+off); off += (size_t)D_MODEL * D_INNER * 2;
    __hip_bfloat16* zxb   = (__hip_bfloat16*)(ws+off); off += (size_t)NROWS * ZX_STR * 2;
    __hip_bfloat16* xs_bf = (__hip_bfloat16*)(ws+off); off += (size_t)NROWS * 2048 * 2;
    __hip_bfloat16* B_bf  = (__hip_bfloat16*)(ws+off); off += (size_t)NROWS * 128 * 2;
    __hip_bfloat16* C_bf  = (__hip_bfloat16*)(ws+off); off += (size_t)NROWS * 128 * 2;
    float* dtp   = (float*)(ws+off);                   off += (size_t)NROWS * NHEADS * 4;
    float* cumg  = (float*)(ws+off);                   off += (size_t)1024 * Q * 4;
    float* decayg= (float*)(ws+off);                   off += (size_t)1024 * 4;
    __hip_bfloat16* M_bf  = (__hip_bfloat16*)(ws+off); off += (size_t)1024 * 4096 * 2;
    __hip_bfloat16* hst   = (__hip_bfloat16*)(ws+off); off += (size_t)1024 * 8192 * 2;
    float* S = (float*)(ws+off);                       off += (size_t)1024 * 8192 * 4;
    // yws/yg alias S (S dead after rec_kernel, before y_kernel writes)
    float* yws = S;
    __hip_bfloat16* yg = (__hip_bfloat16*)(S + (size_t)NROWS * D_INNER);

    detect_dtype<<<1, 256, 0, stream>>>((const unsigned short*)x_raw, flag);
    to_bf16_all<<<(XN8+WN8+ON8)/256, 256, 0, stream>>>(x_raw, inw_raw, outw_raw,
                                                       xb, inwb, outwb, flag);
    // in_proj: 64x128 tiles -> 34x32 = 1088 blocks (4.25/CU)
    gemm_bt<0,64,128,1,4><<<dim3(34, 32), 256, 0, stream>>>(
        xb, inwb, zxb, nullptr, nullptr, flag, D_MODEL, ZX_STR);
    dt_kernel<<<NROWS, 256, 0, stream>>>(x_raw, inw_raw, dtb, flag, dtp);
    conv_silu<<<NROWS, 256, 0, stream>>>(zxb, convw, convb, flag, xs_bf, B_bf, C_bf);
    // fused cum + GM + S
    chunk_kernel<<<1024, 256, 0, stream>>>(xs_bf, B_bf, C_bf, dtp, Alog, flag,
                                           cumg, decayg, M_bf, S);
    rec_kernel<<<512, 256, 0, stream>>>(S, decayg, hst);
    y_kernel<<<1024, 256, 0, stream>>>(M_bf, xs_bf, C_bf, hst, cumg, Dsk, flag, yws);
    gate_norm<<<NROWS, 256, 0, stream>>>(yws, zxb, normw, flag, yg);
    // out_proj: 64x64 tiles -> 16x32 = 512 blocks (2/CU)
    gemm_bt<1,64,64,2,2><<<dim3(16, 32), 256, 0, stream>>>(
        yg, outwb, nullptr, x_raw, d_out, flag, D_INNER, D_MODEL);
}

// Round 5
// 256.702 us; speedup vs baseline: 2.8924x; 1.0335x over previous
//
#include <hip/hip_runtime.h>
#include <hip/hip_bf16.h>
#include <math.h>

#define NHEADS   32
#define CONV_DIM 2304
#define D_INNER  2048
#define SEQLEN   1024
#define NROWS    2048     // BATCH*SEQLEN
#define ZX_STR   4352     // z(2048) + xBC(2304); dt columns handled separately
#define D_MODEL  1024
#define Q        64       // chunk length
#define NCHUNK   16       // SEQLEN / Q
#define XT_STR   72       // LDS transpose row stride (shorts): 144B = 16B-aligned

typedef __attribute__((ext_vector_type(8))) short bhalf8;
typedef __attribute__((ext_vector_type(8))) short short8;
typedef __attribute__((ext_vector_type(4))) short short4v;
typedef __attribute__((ext_vector_type(4))) float f32x4;

__device__ __forceinline__ float bf2f(__hip_bfloat16 v){ return __bfloat162float(v); }
__device__ __forceinline__ short f2bs(float f){ __hip_bfloat16 h = __float2bfloat16(f); return *(short*)&h; }
__device__ __forceinline__ float s2f(short s){ __hip_bfloat16 h = *(__hip_bfloat16*)&s; return __bfloat162float(h); }
__device__ __forceinline__ float rdin(const void* p, size_t i, int isf){
    return isf ? ((const float*)p)[i] : __bfloat162float(((const __hip_bfloat16*)p)[i]);
}

// ---------------------------------------------------------------------------
// Dtype detection (fp32 vs bf16 inputs): vote on exponent sanity of even halves.
// ---------------------------------------------------------------------------
__global__ __launch_bounds__(256)
void detect_dtype(const unsigned short* __restrict__ p, int* __restrict__ flag)
{
    int cnt = 0;
    for (int i = threadIdx.x; i < 4096; i += 256) {
        unsigned short u = p[2 * i];
        int e = (u >> 7) & 0xFF;
        cnt += (e >= 90 && e <= 141) ? 1 : 0;
    }
#pragma unroll
    for (int m = 1; m < 64; m <<= 1) cnt += __shfl_xor(cnt, m);
    __shared__ int red[4];
    if ((threadIdx.x & 63) == 0) red[threadIdx.x >> 6] = cnt;
    __syncthreads();
    if (threadIdx.x == 0) *flag = ((red[0]+red[1]+red[2]+red[3]) < 2048) ? 1 : 0;
}

// ---------------------------------------------------------------------------
// One fused normalize pass for x / in_proj_w / out_proj_w -> canonical bf16.
// ---------------------------------------------------------------------------
#define XN8 262144   // 2048*1024/8
#define WN8 561152   // 4384*1024/8
#define ON8 262144   // 2048*1024/8
__global__ __launch_bounds__(256)
void to_bf16_all(const void* __restrict__ xs, const void* __restrict__ ws,
                 const void* __restrict__ os,
                 __hip_bfloat16* __restrict__ xd, __hip_bfloat16* __restrict__ wd,
                 __hip_bfloat16* __restrict__ od, const int* __restrict__ flagp)
{
    const int isf = *flagp;
    int i = blockIdx.x * 256 + threadIdx.x;
    const void* src; __hip_bfloat16* dst; int j;
    if (i < XN8)            { src = xs; dst = xd; j = i; }
    else if (i < XN8 + WN8) { src = ws; dst = wd; j = i - XN8; }
    else                    { src = os; dst = od; j = i - XN8 - WN8; }
    if (isf) {
        const float4* s = (const float4*)src;
        float4 a = s[2 * j], b = s[2 * j + 1];
        short8 r;
        r[0]=f2bs(a.x); r[1]=f2bs(a.y); r[2]=f2bs(a.z); r[3]=f2bs(a.w);
        r[4]=f2bs(b.x); r[5]=f2bs(b.y); r[6]=f2bs(b.z); r[7]=f2bs(b.w);
        ((short8*)dst)[j] = r;
    } else {
        ((float4*)dst)[j] = ((const float4*)src)[j];
    }
}

// ---------------------------------------------------------------------------
// GEMM C[m,n] = sum_k A[m,k]*W[n,k]. Templated tile MTxNT, 4 waves WROWSxWCOLS.
// LDS layout XOR-SWIZZLED at 16B-segment granularity: element (row, seg) lives
// at segment (seg ^ (row&7)). Staging permutes the SOURCE column per lane
// (global_load_lds dest is fixed at base+lane*16), reads apply the same XOR.
// Kills the 128B-row-stride same-bank serialization (1.0e7 conflict cycles).
// ---------------------------------------------------------------------------
template<int MODE, int MT, int NT, int WROWS, int WCOLS>
__global__ __launch_bounds__(256)
void gemm_bt(const __hip_bfloat16* __restrict__ A,
             const __hip_bfloat16* __restrict__ W,
             __hip_bfloat16* __restrict__ Cb,
             const void* __restrict__ xraw,
             void* __restrict__ outv,
             const int* __restrict__ flagp,
             int K, int N)
{
    constexpr int FM = MT / WROWS / 16;
    constexpr int FN = NT / WCOLS / 16;
    constexpr int AI = MT / 32;          // A-staging instrs per wave
    constexpr int BI = NT / 32;          // B-staging instrs per wave
    __shared__ short As[MT * 64];
    __shared__ short Bs[NT * 64];
    const int m0 = blockIdx.y * MT;
    const int n0 = blockIdx.x * NT;
    const int wave = threadIdx.x >> 6;
    const int lane = threadIdx.x & 63;
    const int lr8 = lane >> 3, lc8 = lane & 7;
    const int lr  = lane & 15, lq  = lane >> 4;
    const int wm = (wave / WCOLS) * (MT / WROWS);
    const int wn = (wave % WCOLS) * (NT / WCOLS);
    const int swl = lr & 7;              // row&7 for all fragment rows this lane reads

    f32x4 acc[FM][FN];
#pragma unroll
    for (int i = 0; i < FM; ++i)
#pragma unroll
        for (int j = 0; j < FN; ++j) acc[i][j] = (f32x4){0.f,0.f,0.f,0.f};

    for (int k0 = 0; k0 < K; k0 += 64) {
#pragma unroll
        for (int i = 0; i < AI; ++i) {
            const int rt = (wave * AI + i) * 8;
            // swizzled source column: segment lc8 ^ (row&7), row&7 == lr8
            const __hip_bfloat16* gp = A + (size_t)(m0 + rt + lr8) * K + k0 + ((lc8 ^ lr8) << 3);
            __builtin_amdgcn_global_load_lds(
                (const __attribute__((address_space(1))) void*)gp,
                (__attribute__((address_space(3))) void*)&As[rt * 64], 16, 0, 0);
        }
#pragma unroll
        for (int i = 0; i < BI; ++i) {
            const int rt = (wave * BI + i) * 8;
            const __hip_bfloat16* gp = W + (size_t)(n0 + rt + lr8) * K + k0 + ((lc8 ^ lr8) << 3);
            __builtin_amdgcn_global_load_lds(
                (const __attribute__((address_space(1))) void*)gp,
                (__attribute__((address_space(3))) void*)&Bs[rt * 64], 16, 0, 0);
        }
        __syncthreads();
#pragma unroll
        for (int kk = 0; kk < 64; kk += 32) {
            const int sw = (((kk >> 3) + lq) ^ swl) << 3;   // swizzled segment offset
            bhalf8 af[FM], bfv[FN];
#pragma unroll
            for (int t = 0; t < FM; ++t)
                af[t]  = *(const bhalf8*)&As[(wm + t * 16 + lr) * 64 + sw];
#pragma unroll
            for (int t = 0; t < FN; ++t)
                bfv[t] = *(const bhalf8*)&Bs[(wn + t * 16 + lr) * 64 + sw];
#pragma unroll
            for (int ti = 0; ti < FM; ++ti)
#pragma unroll
                for (int tj = 0; tj < FN; ++tj)
                    acc[ti][tj] = __builtin_amdgcn_mfma_f32_16x16x32_bf16(
                        af[ti], bfv[tj], acc[ti][tj], 0, 0, 0);
        }
        __syncthreads();
    }

    const int isf = (MODE == 1) ? *flagp : 0;
#pragma unroll
    for (int ti = 0; ti < FM; ++ti)
#pragma unroll
        for (int tj = 0; tj < FN; ++tj)
#pragma unroll
            for (int r = 0; r < 4; ++r) {
                int m = m0 + wm + ti * 16 + lq * 4 + r;
                int n = n0 + wn + tj * 16 + lr;
                size_t idx = (size_t)m * N + n;
                float v = acc[ti][tj][r];
                if (MODE == 0) {
                    Cb[idx] = __float2bfloat16(v);
                } else {
                    v += rdin(xraw, idx, isf);     // residual from RAW x
                    if (isf) ((float*)outv)[idx] = v;
                    else     ((__hip_bfloat16*)outv)[idx] = __float2bfloat16(v);
                }
            }
}

// ---------------------------------------------------------------------------
// fp32 dt path from RAW inputs, 8 rows/block (256 blocks): W_dt L2 traffic
// 268 -> 33 MB. dtp = softplus(x·W_dt + dt_bias).
// ---------------------------------------------------------------------------
__global__ __launch_bounds__(256)
void dt_kernel(const void* __restrict__ xraw, const void* __restrict__ wraw,
               const void* __restrict__ dt_bias,
               const int* __restrict__ flagp,
               float* __restrict__ dtp)
{
    const int isf = *flagp;
    const int r0 = blockIdx.x * 8;
    __shared__ float xs[8][D_MODEL];
    for (int idx = threadIdx.x; idx < 8 * D_MODEL; idx += 256)
        ((float*)xs)[idx] = rdin(xraw, (size_t)r0 * D_MODEL + idx, isf);
    __syncthreads();
    const int h = threadIdx.x >> 3;   // 32 heads
    const int t = threadIdx.x & 7;    // 8 threads/head
    const size_t wbase = (size_t)(4352 + h) * D_MODEL;
    float s[8];
#pragma unroll
    for (int r = 0; r < 8; ++r) s[r] = 0.f;
    for (int k = t; k < D_MODEL; k += 8) {
        float wv = rdin(wraw, wbase + k, isf);
#pragma unroll
        for (int r = 0; r < 8; ++r) s[r] = fmaf(xs[r][k], wv, s[r]);
    }
#pragma unroll
    for (int r = 0; r < 8; ++r) {
        s[r] += __shfl_xor(s[r], 1);
        s[r] += __shfl_xor(s[r], 2);
        s[r] += __shfl_xor(s[r], 4);
    }
    if (t == 0) {
        float bias = rdin(dt_bias, h, isf);
#pragma unroll
        for (int r = 0; r < 8; ++r) {
            float raw = s[r] + bias;
            dtp[(size_t)(r0 + r) * NHEADS + h] = raw > 20.f ? raw : log1pf(expf(raw));
        }
    }
}

// ---------------------------------------------------------------------------
// Depthwise causal conv(4) + bias + SiLU, 8 rows/block (256 blocks).
// 11 input rows staged in LDS (vs 4 reads/row before). -> split xs/B/C bf16.
// ---------------------------------------------------------------------------
__global__ __launch_bounds__(256)
void conv_silu(const __hip_bfloat16* __restrict__ zxb,
               const void* __restrict__ conv_w, const void* __restrict__ conv_b,
               const int* __restrict__ flagp,
               __hip_bfloat16* __restrict__ xs_bf,
               __hip_bfloat16* __restrict__ B_bf,
               __hip_bfloat16* __restrict__ C_bf)
{
    __shared__ short buf[11 * CONV_DIM];
    const int isf = *flagp;
    const int r0 = blockIdx.x * 8;              // first output row
    const int bstart = r0 & ~(SEQLEN - 1);      // batch's first row
    // stage rows r0-3 .. r0+7 (local 0..10); zeros where before batch start
    for (int idx = threadIdx.x; idx < 11 * (CONV_DIM / 8); idx += 256) {
        int ii = idx / (CONV_DIM / 8);
        int seg = idx % (CONV_DIM / 8);
        int g = r0 - 3 + ii;
        bhalf8 v;
        if (g >= bstart) {
            v = *(const bhalf8*)&zxb[(size_t)g * ZX_STR + 2048 + seg * 8];
        } else {
#pragma unroll
            for (int j = 0; j < 8; ++j) v[j] = 0;
        }
        *(bhalf8*)&buf[ii * CONV_DIM + seg * 8] = v;
    }
    __syncthreads();

#pragma unroll
    for (int j = 0; j < CONV_DIM / 256; ++j) {   // 9 channels per thread
        const int c = threadIdx.x + j * 256;
        float w0 = rdin(conv_w, (size_t)c * 4 + 0, isf);
        float w1 = rdin(conv_w, (size_t)c * 4 + 1, isf);
        float w2 = rdin(conv_w, (size_t)c * 4 + 2, isf);
        float w3 = rdin(conv_w, (size_t)c * 4 + 3, isf);
        float bias = rdin(conv_b, c, isf);
#pragma unroll
        for (int r = 0; r < 8; ++r) {
            float acc = bias;
            acc = fmaf(s2f(buf[(r + 0) * CONV_DIM + c]), w0, acc);
            acc = fmaf(s2f(buf[(r + 1) * CONV_DIM + c]), w1, acc);
            acc = fmaf(s2f(buf[(r + 2) * CONV_DIM + c]), w2, acc);
            acc = fmaf(s2f(buf[(r + 3) * CONV_DIM + c]), w3, acc);
            float v = acc / (1.f + expf(-acc));
            __hip_bfloat16 bv = __float2bfloat16(v);
            int row = r0 + r;
            if (c < 2048)       xs_bf[(size_t)row * 2048 + c] = bv;
            else if (c < 2176)  B_bf[(size_t)row * 128 + (c - 2048)] = bv;
            else                C_bf[(size_t)row * 128 + (c - 2176)] = bv;
        }
    }
}

// ---------------------------------------------------------------------------
// FUSED per-(b,h,chunk) kernel: [cum scan] + [GM: masked C·B^T] + [S: u-scaled
// X^T·B]. Grid 1024 blocks x 256 thr. cum/u/dt live in LDS between phases.
// ---------------------------------------------------------------------------
__global__ __launch_bounds__(256)
void chunk_kernel(const __hip_bfloat16* __restrict__ xs_bf,
                  const __hip_bfloat16* __restrict__ B_bf,
                  const __hip_bfloat16* __restrict__ C_bf,
                  const float* __restrict__ dtp, const void* __restrict__ Alog,
                  const int* __restrict__ flagp,
                  float* __restrict__ cumg, float* __restrict__ decayg,
                  __hip_bfloat16* __restrict__ M_bf, float* __restrict__ S)
{
    __shared__ float cumS[Q], uS[Q], dtS[Q];
    __shared__ short Xt[64 * XT_STR];
    __shared__ short Bt[128 * XT_STR];
    const int bhc = blockIdx.x;
    const int c = bhc & 15, h = (bhc >> 4) & 31, b = bhc >> 9;
    const int row0 = b * SEQLEN + c * Q;
    const int isf = *flagp;

    // ---- phase 0: log-decay prefix scan (wave 0 only) ----
    if (threadIdx.x < 64) {
        const int t = threadIdx.x;
        const float An = -expf(rdin(Alog, h, isf));
        const float dt = dtp[(size_t)(row0 + t) * NHEADS + h];
        float cum = dt * An;
#pragma unroll
        for (int ofs = 1; ofs < 64; ofs <<= 1) {
            float v = __shfl_up(cum, ofs);
            if (t >= ofs) cum += v;
        }
        float tot = __shfl(cum, 63);
        cumS[t] = cum; dtS[t] = dt;
        uS[t] = expf(tot - cum) * dt;
        cumg[(size_t)bhc * Q + t] = cum;          // y_kernel input
        if (t == 63) decayg[bhc] = expf(tot);     // rec_kernel input
    }
    __syncthreads();

    // ---- transposes into LDS (overlap with GM's global loads) ----
#pragma unroll
    for (int i = 0; i < 2; ++i) {
        int seg = threadIdx.x + i * 256;          // 512 segs of 8
        int t = seg >> 3, p8 = (seg & 7) * 8;
        float ut = uS[t];
        bhalf8 v = *(const bhalf8*)&xs_bf[(size_t)(row0 + t) * 2048 + h * 64 + p8];
#pragma unroll
        for (int j = 0; j < 8; ++j)
            Xt[(p8 + j) * XT_STR + t] = f2bs(s2f(v[j]) * ut);
    }
#pragma unroll
    for (int i = 0; i < 4; ++i) {
        int seg = threadIdx.x + i * 256;          // 1024 segs of 8
        int t = seg >> 4, n8 = (seg & 15) * 8;
        bhalf8 v = *(const bhalf8*)&B_bf[(size_t)(row0 + t) * 128 + n8];
#pragma unroll
        for (int j = 0; j < 8; ++j)
            Bt[(n8 + j) * XT_STR + t] = v[j];
    }

    const int wave = threadIdx.x >> 6, lane = threadIdx.x & 63;
    const int lr = lane & 15, lq = lane >> 4;

    // ---- GM phase: G = C·B^T (64x64, K=128), masked-decay -> M_bf ----
    {
        const int t0 = wave * 16;
        f32x4 acc[4];
#pragma unroll
        for (int j = 0; j < 4; ++j) acc[j] = (f32x4){0.f,0.f,0.f,0.f};
#pragma unroll
        for (int kk = 0; kk < 128; kk += 32) {
            bhalf8 af = *(const bhalf8*)&C_bf[(size_t)(row0 + t0 + lr) * 128 + kk + lq * 8];
#pragma unroll
            for (int j = 0; j < 4; ++j) {
                bhalf8 bf = *(const bhalf8*)&B_bf[(size_t)(row0 + j * 16 + lr) * 128 + kk + lq * 8];
                acc[j] = __builtin_amdgcn_mfma_f32_16x16x32_bf16(af, bf, acc[j], 0, 0, 0);
            }
        }
#pragma unroll
        for (int j = 0; j < 4; ++j)
#pragma unroll
            for (int r = 0; r < 4; ++r) {
                int t = t0 + lq * 4 + r;
                int s = j * 16 + lr;
                float m = (s <= t) ? acc[j][r] * expf(cumS[t] - cumS[s]) * dtS[s] : 0.f;
                M_bf[(size_t)bhc * 4096 + t * 64 + s] = __float2bfloat16(m);
            }
    }
    __syncthreads();

    // ---- S phase: S[p,n] = sum_t (u_t x_t[p]) B_t[n]  (64x128, K=64) ----
    {
        const int p0 = wave * 16;
        f32x4 acc[8];
#pragma unroll
        for (int j = 0; j < 8; ++j) acc[j] = (f32x4){0.f,0.f,0.f,0.f};
#pragma unroll
        for (int kk = 0; kk < 64; kk += 32) {
            bhalf8 af = *(const bhalf8*)&Xt[(p0 + lr) * XT_STR + kk + lq * 8];
#pragma unroll
            for (int j = 0; j < 8; ++j) {
                bhalf8 bf = *(const bhalf8*)&Bt[(j * 16 + lr) * XT_STR + kk + lq * 8];
                acc[j] = __builtin_amdgcn_mfma_f32_16x16x32_bf16(af, bf, acc[j], 0, 0, 0);
            }
        }
#pragma unroll
        for (int j = 0; j < 8; ++j)
#pragma unroll
            for (int r = 0; r < 4; ++r) {
                int p = p0 + lq * 4 + r;
                int n = j * 16 + lr;
                S[(size_t)bhc * 8192 + p * 128 + n] = acc[j][r];
            }
    }
}

// ---------------------------------------------------------------------------
// Inter-chunk recurrence (16 serial steps): hstart(c)=h; h = decay*h + S_c.
// ---------------------------------------------------------------------------
__global__ __launch_bounds__(256)
void rec_kernel(const float* __restrict__ S, const float* __restrict__ decayg,
                __hip_bfloat16* __restrict__ hst)
{
    const int bh = blockIdx.x >> 3;
    const int sl = blockIdx.x & 7;
    const int off = sl * 1024 + threadIdx.x * 4;
    float h0 = 0.f, h1 = 0.f, h2 = 0.f, h3 = 0.f;
    for (int c = 0; c < NCHUNK; ++c) {
        size_t base = ((size_t)bh * NCHUNK + c) * 8192 + off;
        short4v hb;
        hb[0] = f2bs(h0); hb[1] = f2bs(h1); hb[2] = f2bs(h2); hb[3] = f2bs(h3);
        *(short4v*)&hst[base] = hb;
        float4 s = *(const float4*)&S[base];
        float d = decayg[bh * NCHUNK + c];
        h0 = fmaf(h0, d, s.x); h1 = fmaf(h1, d, s.y);
        h2 = fmaf(h2, d, s.z); h3 = fmaf(h3, d, s.w);
    }
}

// ---------------------------------------------------------------------------
// Y kernel: Y[t,p] = (M·X)[t,p] + exp(cum_t)*(C·hstart^T)[t,p] + Dh*x[t,p]
// ---------------------------------------------------------------------------
__global__ __launch_bounds__(256)
void y_kernel(const __hip_bfloat16* __restrict__ M_bf,
              const __hip_bfloat16* __restrict__ xs_bf,
              const __hip_bfloat16* __restrict__ C_bf,
              const __hip_bfloat16* __restrict__ hst,
              const float* __restrict__ cumg,
              const void* __restrict__ Draw, const int* __restrict__ flagp,
              float* __restrict__ yws)
{
    __shared__ short Xt[64 * XT_STR];
    const int bhc = blockIdx.x;
    const int c = bhc & 15, h = (bhc >> 4) & 31, b = bhc >> 9;
    const int row0 = b * SEQLEN + c * Q;
    const int isf = *flagp;
    const float Dh = rdin(Draw, h, isf);

#pragma unroll
    for (int i = 0; i < 2; ++i) {
        int seg = threadIdx.x + i * 256;
        int t = seg >> 3, p8 = (seg & 7) * 8;
        bhalf8 v = *(const bhalf8*)&xs_bf[(size_t)(row0 + t) * 2048 + h * 64 + p8];
#pragma unroll
        for (int j = 0; j < 8; ++j)
            Xt[(p8 + j) * XT_STR + t] = v[j];
    }
    __syncthreads();

    const int wave = threadIdx.x >> 6, lane = threadIdx.x & 63;
    const int lr = lane & 15, lq = lane >> 4;
    const int t0 = wave * 16;
    f32x4 acc1[4], acc2[4];
#pragma unroll
    for (int j = 0; j < 4; ++j) { acc1[j] = (f32x4){0.f,0.f,0.f,0.f}; acc2[j] = acc1[j]; }

#pragma unroll
    for (int kk = 0; kk < 64; kk += 32) {
        bhalf8 af = *(const bhalf8*)&M_bf[(size_t)bhc * 4096 + (t0 + lr) * 64 + kk + lq * 8];
#pragma unroll
        for (int j = 0; j < 4; ++j) {
            bhalf8 bf = *(const bhalf8*)&Xt[(j * 16 + lr) * XT_STR + kk + lq * 8];
            acc1[j] = __builtin_amdgcn_mfma_f32_16x16x32_bf16(af, bf, acc1[j], 0, 0, 0);
        }
    }
#pragma unroll
    for (int kk = 0; kk < 128; kk += 32) {
        bhalf8 af = *(const bhalf8*)&C_bf[(size_t)(row0 + t0 + lr) * 128 + kk + lq * 8];
#pragma unroll
        for (int j = 0; j < 4; ++j) {
            bhalf8 bf = *(const bhalf8*)&hst[(size_t)bhc * 8192 + (j * 16 + lr) * 128 + kk + lq * 8];
            acc2[j] = __builtin_amdgcn_mfma_f32_16x16x32_bf16(af, bf, acc2[j], 0, 0, 0);
        }
    }
    float ex[4];
#pragma unroll
    for (int r = 0; r < 4; ++r) ex[r] = expf(cumg[(size_t)bhc * Q + t0 + lq * 4 + r]);
#pragma unroll
    for (int j = 0; j < 4; ++j)
#pragma unroll
        for (int r = 0; r < 4; ++r) {
            int t = t0 + lq * 4 + r;
            int p = j * 16 + lr;
            float xv = s2f(Xt[p * XT_STR + t]);
            float y = acc1[j][r] + ex[r] * acc2[j][r] + Dh * xv;
            yws[(size_t)(row0 + t) * D_INNER + h * 64 + p] = y;
        }
}

// ---------------------------------------------------------------------------
// y*silu(z) -> RMSNorm -> *norm_w -> bf16
// ---------------------------------------------------------------------------
__global__ __launch_bounds__(256)
void gate_norm(const float* __restrict__ yws,
               const __hip_bfloat16* __restrict__ zxb,
               const void* __restrict__ norm_w,
               const int* __restrict__ flagp,
               __hip_bfloat16* __restrict__ yg)
{
    const int isf = *flagp;
    const int row = blockIdx.x;
    const float* y = yws + (size_t)row * D_INNER;
    const __hip_bfloat16* z = zxb + (size_t)row * ZX_STR;
    float v[8]; float ss = 0.f;
#pragma unroll
    for (int it = 0; it < 8; ++it) {
        int c = it * 256 + threadIdx.x;
        float zz = bf2f(z[c]);
        float vv = y[c] * (zz / (1.f + expf(-zz)));
        v[it] = vv;
        ss += vv * vv;
    }
#pragma unroll
    for (int m = 1; m < 64; m <<= 1) ss += __shfl_xor(ss, m);
    __shared__ float red[4];
    if ((threadIdx.x & 63) == 0) red[threadIdx.x >> 6] = ss;
    __syncthreads();
    float tot = red[0] + red[1] + red[2] + red[3];
    float scale = rsqrtf(tot / (float)D_INNER + 1e-5f);
#pragma unroll
    for (int it = 0; it < 8; ++it) {
        int c = it * 256 + threadIdx.x;
        yg[(size_t)row * D_INNER + c] =
            __float2bfloat16(v[it] * scale * rdin(norm_w, c, isf));
    }
}

extern "C" void kernel_launch(void* const* d_in, const int* in_sizes, int n_in,
                              void* d_out, int out_size, void* d_ws, size_t ws_size,
                              hipStream_t stream)
{
    const void* x_raw    = d_in[0];
    const void* inw_raw  = d_in[1];
    const void* convw    = d_in[2];
    const void* convb    = d_in[3];
    const void* dtb      = d_in[4];
    const void* Alog     = d_in[5];
    const void* Dsk      = d_in[6];
    const void* normw    = d_in[7];
    const void* outw_raw = d_in[8];

    char* ws = (char*)d_ws;
    size_t off = 0;
    int* flag = (int*)(ws + off);                      off += 256;
    __hip_bfloat16* xb    = (__hip_bfloat16*)(ws+off); off += (size_t)NROWS * D_MODEL * 2;
    __hip_bfloat16* inwb  = (__hip_bfloat16*)(ws+off); off += (size_t)4384 * D_MODEL * 2;
    __hip_bfloat16* outwb = (__hip_bfloat16*)(ws+off); off += (size_t)D_MODEL * D_INNER * 2;
    __hip_bfloat16* zxb   = (__hip_bfloat16*)(ws+off); off += (size_t)NROWS * ZX_STR * 2;
    __hip_bfloat16* xs_bf = (__hip_bfloat16*)(ws+off); off += (size_t)NROWS * 2048 * 2;
    __hip_bfloat16* B_bf  = (__hip_bfloat16*)(ws+off); off += (size_t)NROWS * 128 * 2;
    __hip_bfloat16* C_bf  = (__hip_bfloat16*)(ws+off); off += (size_t)NROWS * 128 * 2;
    float* dtp   = (float*)(ws+off);                   off += (size_t)NROWS * NHEADS * 4;
    float* cumg  = (float*)(ws+off);                   off += (size_t)1024 * Q * 4;
    float* decayg= (float*)(ws+off);                   off += (size_t)1024 * 4;
    __hip_bfloat16* M_bf  = (__hip_bfloat16*)(ws+off); off += (size_t)1024 * 4096 * 2;
    __hip_bfloat16* hst   = (__hip_bfloat16*)(ws+off); off += (size_t)1024 * 8192 * 2;
    float* S = (float*)(ws+off);                       off += (size_t)1024 * 8192 * 4;
    // yws/yg alias S (S dead after rec_kernel, before y_kernel writes)
    float* yws = S;
    __hip_bfloat16* yg = (__hip_bfloat16*)(S + (size_t)NROWS * D_INNER);

    detect_dtype<<<1, 256, 0, stream>>>((const unsigned short*)x_raw, flag);
    to_bf16_all<<<(XN8+WN8+ON8)/256, 256, 0, stream>>>(x_raw, inw_raw, outw_raw,
                                                       xb, inwb, outwb, flag);
    // in_proj: 64x128 tiles -> 34x32 = 1088 blocks (4.25/CU)
    gemm_bt<0,64,128,1,4><<<dim3(34, 32), 256, 0, stream>>>(
        xb, inwb, zxb, nullptr, nullptr, flag, D_MODEL, ZX_STR);
    dt_kernel<<<256, 256, 0, stream>>>(x_raw, inw_raw, dtb, flag, dtp);
    conv_silu<<<256, 256, 0, stream>>>(zxb, convw, convb, flag, xs_bf, B_bf, C_bf);
    // fused cum + GM + S
    chunk_kernel<<<1024, 256, 0, stream>>>(xs_bf, B_bf, C_bf, dtp, Alog, flag,
                                           cumg, decayg, M_bf, S);
    rec_kernel<<<512, 256, 0, stream>>>(S, decayg, hst);
    y_kernel<<<1024, 256, 0, stream>>>(M_bf, xs_bf, C_bf, hst, cumg, Dsk, flag, yws);
    gate_norm<<<NROWS, 256, 0, stream>>>(yws, zxb, normw, flag, yg);
    // out_proj: 64x64 tiles -> 16x32 = 512 blocks (2/CU)
    gemm_bt<1,64,64,2,2><<<dim3(16, 32), 256, 0, stream>>>(
        yg, outwb, nullptr, x_raw, d_out, flag, D_INNER, D_MODEL);
}

// Round 6
// 248.814 us; speedup vs baseline: 2.9841x; 1.0317x over previous
//
#include <hip/hip_runtime.h>
#include <hip/hip_bf16.h>
#include <math.h>

#define NHEADS   32
#define CONV_DIM 2304
#define D_INNER  2048
#define SEQLEN   1024
#define NROWS    2048     // BATCH*SEQLEN
#define ZX_STR   4352     // z(2048) + xBC(2304); dt columns handled separately
#define D_MODEL  1024
#define Q        64       // chunk length
#define NCHUNK   16       // SEQLEN / Q
#define XT_STR   72       // LDS transpose row stride (shorts): 144B = 16B-aligned

typedef __attribute__((ext_vector_type(8))) short bhalf8;
typedef __attribute__((ext_vector_type(8))) short short8;
typedef __attribute__((ext_vector_type(4))) short short4v;
typedef __attribute__((ext_vector_type(4))) float f32x4;

__device__ __forceinline__ float bf2f(__hip_bfloat16 v){ return __bfloat162float(v); }
__device__ __forceinline__ short f2bs(float f){ __hip_bfloat16 h = __float2bfloat16(f); return *(short*)&h; }
__device__ __forceinline__ float s2f(short s){ __hip_bfloat16 h = *(__hip_bfloat16*)&s; return __bfloat162float(h); }
__device__ __forceinline__ float rdin(const void* p, size_t i, int isf){
    return isf ? ((const float*)p)[i] : __bfloat162float(((const __hip_bfloat16*)p)[i]);
}

// ---------------------------------------------------------------------------
// Dtype detection + rowsum zeroing (rowsum feeds y_kernel atomics).
// ---------------------------------------------------------------------------
__global__ __launch_bounds__(256)
void detect_dtype(const unsigned short* __restrict__ p, int* __restrict__ flag,
                  float* __restrict__ rowsum)
{
    for (int i = threadIdx.x; i < NROWS; i += 256) rowsum[i] = 0.f;
    int cnt = 0;
    for (int i = threadIdx.x; i < 4096; i += 256) {
        unsigned short u = p[2 * i];
        int e = (u >> 7) & 0xFF;
        cnt += (e >= 90 && e <= 141) ? 1 : 0;
    }
#pragma unroll
    for (int m = 1; m < 64; m <<= 1) cnt += __shfl_xor(cnt, m);
    __shared__ int red[4];
    if ((threadIdx.x & 63) == 0) red[threadIdx.x >> 6] = cnt;
    __syncthreads();
    if (threadIdx.x == 0) *flag = ((red[0]+red[1]+red[2]+red[3]) < 2048) ? 1 : 0;
}

// ---------------------------------------------------------------------------
// One fused normalize pass for x / in_proj_w / out_proj_w -> canonical bf16.
// ---------------------------------------------------------------------------
#define XN8 262144   // 2048*1024/8
#define WN8 561152   // 4384*1024/8
#define ON8 262144   // 2048*1024/8
__global__ __launch_bounds__(256)
void to_bf16_all(const void* __restrict__ xs, const void* __restrict__ ws,
                 const void* __restrict__ os,
                 __hip_bfloat16* __restrict__ xd, __hip_bfloat16* __restrict__ wd,
                 __hip_bfloat16* __restrict__ od, const int* __restrict__ flagp)
{
    const int isf = *flagp;
    int i = blockIdx.x * 256 + threadIdx.x;
    const void* src; __hip_bfloat16* dst; int j;
    if (i < XN8)            { src = xs; dst = xd; j = i; }
    else if (i < XN8 + WN8) { src = ws; dst = wd; j = i - XN8; }
    else                    { src = os; dst = od; j = i - XN8 - WN8; }
    if (isf) {
        const float4* s = (const float4*)src;
        float4 a = s[2 * j], b = s[2 * j + 1];
        short8 r;
        r[0]=f2bs(a.x); r[1]=f2bs(a.y); r[2]=f2bs(a.z); r[3]=f2bs(a.w);
        r[4]=f2bs(b.x); r[5]=f2bs(b.y); r[6]=f2bs(b.z); r[7]=f2bs(b.w);
        ((short8*)dst)[j] = r;
    } else {
        ((float4*)dst)[j] = ((const float4*)src)[j];
    }
}

// ---------------------------------------------------------------------------
// GEMM C[m,n] = sum_k A[m,k]*W[n,k]. XOR-swizzled LDS (16B segments).
// MODE 0: bf16 store. MODE 1: + raw-x residual, flag-dtype store.
// ---------------------------------------------------------------------------
template<int MODE, int MT, int NT, int WROWS, int WCOLS>
__global__ __launch_bounds__(256)
void gemm_bt(const __hip_bfloat16* __restrict__ A,
             const __hip_bfloat16* __restrict__ W,
             __hip_bfloat16* __restrict__ Cb,
             const void* __restrict__ xraw,
             void* __restrict__ outv,
             const int* __restrict__ flagp,
             int K, int N)
{
    constexpr int FM = MT / WROWS / 16;
    constexpr int FN = NT / WCOLS / 16;
    constexpr int AI = MT / 32;
    constexpr int BI = NT / 32;
    __shared__ short As[MT * 64];
    __shared__ short Bs[NT * 64];
    const int m0 = blockIdx.y * MT;
    const int n0 = blockIdx.x * NT;
    const int wave = threadIdx.x >> 6;
    const int lane = threadIdx.x & 63;
    const int lr8 = lane >> 3, lc8 = lane & 7;
    const int lr  = lane & 15, lq  = lane >> 4;
    const int wm = (wave / WCOLS) * (MT / WROWS);
    const int wn = (wave % WCOLS) * (NT / WCOLS);
    const int swl = lr & 7;

    f32x4 acc[FM][FN];
#pragma unroll
    for (int i = 0; i < FM; ++i)
#pragma unroll
        for (int j = 0; j < FN; ++j) acc[i][j] = (f32x4){0.f,0.f,0.f,0.f};

    for (int k0 = 0; k0 < K; k0 += 64) {
#pragma unroll
        for (int i = 0; i < AI; ++i) {
            const int rt = (wave * AI + i) * 8;
            const __hip_bfloat16* gp = A + (size_t)(m0 + rt + lr8) * K + k0 + ((lc8 ^ lr8) << 3);
            __builtin_amdgcn_global_load_lds(
                (const __attribute__((address_space(1))) void*)gp,
                (__attribute__((address_space(3))) void*)&As[rt * 64], 16, 0, 0);
        }
#pragma unroll
        for (int i = 0; i < BI; ++i) {
            const int rt = (wave * BI + i) * 8;
            const __hip_bfloat16* gp = W + (size_t)(n0 + rt + lr8) * K + k0 + ((lc8 ^ lr8) << 3);
            __builtin_amdgcn_global_load_lds(
                (const __attribute__((address_space(1))) void*)gp,
                (__attribute__((address_space(3))) void*)&Bs[rt * 64], 16, 0, 0);
        }
        __syncthreads();
#pragma unroll
        for (int kk = 0; kk < 64; kk += 32) {
            const int sw = (((kk >> 3) + lq) ^ swl) << 3;
            bhalf8 af[FM], bfv[FN];
#pragma unroll
            for (int t = 0; t < FM; ++t)
                af[t]  = *(const bhalf8*)&As[(wm + t * 16 + lr) * 64 + sw];
#pragma unroll
            for (int t = 0; t < FN; ++t)
                bfv[t] = *(const bhalf8*)&Bs[(wn + t * 16 + lr) * 64 + sw];
#pragma unroll
            for (int ti = 0; ti < FM; ++ti)
#pragma unroll
                for (int tj = 0; tj < FN; ++tj)
                    acc[ti][tj] = __builtin_amdgcn_mfma_f32_16x16x32_bf16(
                        af[ti], bfv[tj], acc[ti][tj], 0, 0, 0);
        }
        __syncthreads();
    }

    const int isf = (MODE == 1) ? *flagp : 0;
#pragma unroll
    for (int ti = 0; ti < FM; ++ti)
#pragma unroll
        for (int tj = 0; tj < FN; ++tj)
#pragma unroll
            for (int r = 0; r < 4; ++r) {
                int m = m0 + wm + ti * 16 + lq * 4 + r;
                int n = n0 + wn + tj * 16 + lr;
                size_t idx = (size_t)m * N + n;
                float v = acc[ti][tj][r];
                if (MODE == 0) {
                    Cb[idx] = __float2bfloat16(v);
                } else {
                    v += rdin(xraw, idx, isf);
                    if (isf) ((float*)outv)[idx] = v;
                    else     ((__hip_bfloat16*)outv)[idx] = __float2bfloat16(v);
                }
            }
}

// ---------------------------------------------------------------------------
// MERGED conv+dt kernel (grid 512). Blocks 0-255: depthwise causal conv(4) +
// bias + SiLU, 8 rows/block, segment-contiguous channels -> bhalf8 stores.
// Blocks 256-511: fp32 dt path (softplus(x·W_dt + dt_bias)), 8 rows/block.
// LDS overlaid (conv 50.7KB short buf; dt reuses as 32KB float).
// ---------------------------------------------------------------------------
__global__ __launch_bounds__(256)
void convdt(const __hip_bfloat16* __restrict__ zxb,
            const void* __restrict__ conv_w, const void* __restrict__ conv_b,
            const void* __restrict__ xraw, const void* __restrict__ wraw,
            const void* __restrict__ dt_bias,
            const int* __restrict__ flagp,
            __hip_bfloat16* __restrict__ xs_bf,
            __hip_bfloat16* __restrict__ B_bf,
            __hip_bfloat16* __restrict__ C_bf,
            float* __restrict__ dtp)
{
    __shared__ short smem[11 * CONV_DIM];     // 50.7 KB (dt aliases 32 KB as float)
    const int isf = *flagp;

    if (blockIdx.x < 256) {
        // ---------------- conv role ----------------
        const int r0 = blockIdx.x * 8;
        const int bstart = r0 & ~(SEQLEN - 1);
        for (int idx = threadIdx.x; idx < 11 * (CONV_DIM / 8); idx += 256) {
            int ii = idx / (CONV_DIM / 8);
            int seg = idx % (CONV_DIM / 8);
            int g = r0 - 3 + ii;
            bhalf8 v;
            if (g >= bstart) {
                v = *(const bhalf8*)&zxb[(size_t)g * ZX_STR + 2048 + seg * 8];
            } else {
#pragma unroll
                for (int j = 0; j < 8; ++j) v[j] = 0;
            }
            *(bhalf8*)&smem[ii * CONV_DIM + seg * 8] = v;
        }
        __syncthreads();

#pragma unroll
        for (int sIt = 0; sIt < 2; ++sIt) {
            const int seg = threadIdx.x + sIt * 256;
            if (seg >= CONV_DIM / 8) break;
            const int c0 = seg * 8;
            float w0[8], w1[8], w2[8], w3[8], bias[8];
#pragma unroll
            for (int j = 0; j < 8; ++j) {
                bias[j] = rdin(conv_b, c0 + j, isf);
                w0[j] = rdin(conv_w, (size_t)(c0 + j) * 4 + 0, isf);
                w1[j] = rdin(conv_w, (size_t)(c0 + j) * 4 + 1, isf);
                w2[j] = rdin(conv_w, (size_t)(c0 + j) * 4 + 2, isf);
                w3[j] = rdin(conv_w, (size_t)(c0 + j) * 4 + 3, isf);
            }
#pragma unroll
            for (int r = 0; r < 8; ++r) {
                bhalf8 i0 = *(const bhalf8*)&smem[(r + 0) * CONV_DIM + c0];
                bhalf8 i1 = *(const bhalf8*)&smem[(r + 1) * CONV_DIM + c0];
                bhalf8 i2 = *(const bhalf8*)&smem[(r + 2) * CONV_DIM + c0];
                bhalf8 i3 = *(const bhalf8*)&smem[(r + 3) * CONV_DIM + c0];
                bhalf8 out;
#pragma unroll
                for (int j = 0; j < 8; ++j) {
                    float acc = bias[j];
                    acc = fmaf(s2f(i0[j]), w0[j], acc);
                    acc = fmaf(s2f(i1[j]), w1[j], acc);
                    acc = fmaf(s2f(i2[j]), w2[j], acc);
                    acc = fmaf(s2f(i3[j]), w3[j], acc);
                    out[j] = f2bs(acc / (1.f + expf(-acc)));
                }
                const int row = r0 + r;
                if (c0 < 2048)
                    *(bhalf8*)&xs_bf[(size_t)row * 2048 + c0] = out;
                else if (c0 < 2176)
                    *(bhalf8*)&B_bf[(size_t)row * 128 + (c0 - 2048)] = out;
                else
                    *(bhalf8*)&C_bf[(size_t)row * 128 + (c0 - 2176)] = out;
            }
        }
    } else {
        // ---------------- dt role ----------------
        float* xsh = (float*)smem;            // 8*1024 floats
        const int r0 = (blockIdx.x - 256) * 8;
        for (int idx = threadIdx.x; idx < 8 * D_MODEL; idx += 256)
            xsh[idx] = rdin(xraw, (size_t)r0 * D_MODEL + idx, isf);
        __syncthreads();
        const int h = threadIdx.x >> 3;
        const int t = threadIdx.x & 7;
        const size_t wbase = (size_t)(4352 + h) * D_MODEL;
        float s[8];
#pragma unroll
        for (int r = 0; r < 8; ++r) s[r] = 0.f;
        for (int k = t; k < D_MODEL; k += 8) {
            float wv = rdin(wraw, wbase + k, isf);
#pragma unroll
            for (int r = 0; r < 8; ++r) s[r] = fmaf(xsh[r * D_MODEL + k], wv, s[r]);
        }
#pragma unroll
        for (int r = 0; r < 8; ++r) {
            s[r] += __shfl_xor(s[r], 1);
            s[r] += __shfl_xor(s[r], 2);
            s[r] += __shfl_xor(s[r], 4);
        }
        if (t == 0) {
            float bias = rdin(dt_bias, h, isf);
#pragma unroll
            for (int r = 0; r < 8; ++r) {
                float raw = s[r] + bias;
                dtp[(size_t)(r0 + r) * NHEADS + h] = raw > 20.f ? raw : log1pf(expf(raw));
            }
        }
    }
}

// ---------------------------------------------------------------------------
// FUSED per-(b,h,chunk): [cum scan] + [GM: masked C·B^T] + [S: u-scaled X^T·B].
// S now stored bf16 (halves the S stream).
// ---------------------------------------------------------------------------
__global__ __launch_bounds__(256)
void chunk_kernel(const __hip_bfloat16* __restrict__ xs_bf,
                  const __hip_bfloat16* __restrict__ B_bf,
                  const __hip_bfloat16* __restrict__ C_bf,
                  const float* __restrict__ dtp, const void* __restrict__ Alog,
                  const int* __restrict__ flagp,
                  float* __restrict__ cumg, float* __restrict__ decayg,
                  __hip_bfloat16* __restrict__ M_bf,
                  __hip_bfloat16* __restrict__ Sb)
{
    __shared__ float cumS[Q], uS[Q], dtS[Q];
    __shared__ short Xt[64 * XT_STR];
    __shared__ short Bt[128 * XT_STR];
    const int bhc = blockIdx.x;
    const int c = bhc & 15, h = (bhc >> 4) & 31, b = bhc >> 9;
    const int row0 = b * SEQLEN + c * Q;
    const int isf = *flagp;

    if (threadIdx.x < 64) {
        const int t = threadIdx.x;
        const float An = -expf(rdin(Alog, h, isf));
        const float dt = dtp[(size_t)(row0 + t) * NHEADS + h];
        float cum = dt * An;
#pragma unroll
        for (int ofs = 1; ofs < 64; ofs <<= 1) {
            float v = __shfl_up(cum, ofs);
            if (t >= ofs) cum += v;
        }
        float tot = __shfl(cum, 63);
        cumS[t] = cum; dtS[t] = dt;
        uS[t] = expf(tot - cum) * dt;
        cumg[(size_t)bhc * Q + t] = cum;
        if (t == 63) decayg[bhc] = expf(tot);
    }
    __syncthreads();

#pragma unroll
    for (int i = 0; i < 2; ++i) {
        int seg = threadIdx.x + i * 256;
        int t = seg >> 3, p8 = (seg & 7) * 8;
        float ut = uS[t];
        bhalf8 v = *(const bhalf8*)&xs_bf[(size_t)(row0 + t) * 2048 + h * 64 + p8];
#pragma unroll
        for (int j = 0; j < 8; ++j)
            Xt[(p8 + j) * XT_STR + t] = f2bs(s2f(v[j]) * ut);
    }
#pragma unroll
    for (int i = 0; i < 4; ++i) {
        int seg = threadIdx.x + i * 256;
        int t = seg >> 4, n8 = (seg & 15) * 8;
        bhalf8 v = *(const bhalf8*)&B_bf[(size_t)(row0 + t) * 128 + n8];
#pragma unroll
        for (int j = 0; j < 8; ++j)
            Bt[(n8 + j) * XT_STR + t] = v[j];
    }

    const int wave = threadIdx.x >> 6, lane = threadIdx.x & 63;
    const int lr = lane & 15, lq = lane >> 4;

    // ---- GM: G = C·B^T (64x64, K=128), masked-decay -> M_bf ----
    {
        const int t0 = wave * 16;
        f32x4 acc[4];
#pragma unroll
        for (int j = 0; j < 4; ++j) acc[j] = (f32x4){0.f,0.f,0.f,0.f};
#pragma unroll
        for (int kk = 0; kk < 128; kk += 32) {
            bhalf8 af = *(const bhalf8*)&C_bf[(size_t)(row0 + t0 + lr) * 128 + kk + lq * 8];
#pragma unroll
            for (int j = 0; j < 4; ++j) {
                bhalf8 bf = *(const bhalf8*)&B_bf[(size_t)(row0 + j * 16 + lr) * 128 + kk + lq * 8];
                acc[j] = __builtin_amdgcn_mfma_f32_16x16x32_bf16(af, bf, acc[j], 0, 0, 0);
            }
        }
#pragma unroll
        for (int j = 0; j < 4; ++j)
#pragma unroll
            for (int r = 0; r < 4; ++r) {
                int t = t0 + lq * 4 + r;
                int s = j * 16 + lr;
                float m = (s <= t) ? acc[j][r] * expf(cumS[t] - cumS[s]) * dtS[s] : 0.f;
                M_bf[(size_t)bhc * 4096 + t * 64 + s] = __float2bfloat16(m);
            }
    }
    __syncthreads();

    // ---- S: S[p,n] = sum_t (u_t x_t[p]) B_t[n] -> bf16 ----
    {
        const int p0 = wave * 16;
        f32x4 acc[8];
#pragma unroll
        for (int j = 0; j < 8; ++j) acc[j] = (f32x4){0.f,0.f,0.f,0.f};
#pragma unroll
        for (int kk = 0; kk < 64; kk += 32) {
            bhalf8 af = *(const bhalf8*)&Xt[(p0 + lr) * XT_STR + kk + lq * 8];
#pragma unroll
            for (int j = 0; j < 8; ++j) {
                bhalf8 bf = *(const bhalf8*)&Bt[(j * 16 + lr) * XT_STR + kk + lq * 8];
                acc[j] = __builtin_amdgcn_mfma_f32_16x16x32_bf16(af, bf, acc[j], 0, 0, 0);
            }
        }
#pragma unroll
        for (int j = 0; j < 8; ++j)
#pragma unroll
            for (int r = 0; r < 4; ++r) {
                int p = p0 + lq * 4 + r;
                int n = j * 16 + lr;
                Sb[(size_t)bhc * 8192 + p * 128 + n] = __float2bfloat16(acc[j][r]);
            }
    }
}

// ---------------------------------------------------------------------------
// Inter-chunk recurrence (16 serial steps): hstart(c)=h; h = decay*h + S_c.
// ---------------------------------------------------------------------------
__global__ __launch_bounds__(256)
void rec_kernel(const __hip_bfloat16* __restrict__ Sb,
                const float* __restrict__ decayg,
                __hip_bfloat16* __restrict__ hst)
{
    const int bh = blockIdx.x >> 3;
    const int sl = blockIdx.x & 7;
    const int off = sl * 1024 + threadIdx.x * 4;
    float h0 = 0.f, h1 = 0.f, h2 = 0.f, h3 = 0.f;
    for (int c = 0; c < NCHUNK; ++c) {
        size_t base = ((size_t)bh * NCHUNK + c) * 8192 + off;
        short4v hb;
        hb[0] = f2bs(h0); hb[1] = f2bs(h1); hb[2] = f2bs(h2); hb[3] = f2bs(h3);
        *(short4v*)&hst[base] = hb;
        short4v sv = *(const short4v*)&Sb[base];
        float d = decayg[bh * NCHUNK + c];
        h0 = fmaf(h0, d, s2f(sv[0])); h1 = fmaf(h1, d, s2f(sv[1]));
        h2 = fmaf(h2, d, s2f(sv[2])); h3 = fmaf(h3, d, s2f(sv[3]));
    }
}

// ---------------------------------------------------------------------------
// Y kernel + FUSED gating: y = M·X + exp(cum)*C·h^T + Dh*x; v = y*silu(z);
// store v bf16 (LDS-repacked 16B stores); atomicAdd per-row sum(v^2).
// ---------------------------------------------------------------------------
__global__ __launch_bounds__(256)
void y_kernel(const __hip_bfloat16* __restrict__ M_bf,
              const __hip_bfloat16* __restrict__ xs_bf,
              const __hip_bfloat16* __restrict__ C_bf,
              const __hip_bfloat16* __restrict__ hst,
              const float* __restrict__ cumg,
              const __hip_bfloat16* __restrict__ zxb,
              const void* __restrict__ Draw, const int* __restrict__ flagp,
              __hip_bfloat16* __restrict__ vbuf, float* __restrict__ rowsum)
{
    __shared__ short Xt[64 * XT_STR];
    __shared__ short zS[64 * XT_STR];
    const int bhc = blockIdx.x;
    const int c = bhc & 15, h = (bhc >> 4) & 31, b = bhc >> 9;
    const int row0 = b * SEQLEN + c * Q;
    const int isf = *flagp;
    const float Dh = rdin(Draw, h, isf);

#pragma unroll
    for (int i = 0; i < 2; ++i) {
        int seg = threadIdx.x + i * 256;
        int t = seg >> 3, p8 = (seg & 7) * 8;
        bhalf8 v = *(const bhalf8*)&xs_bf[(size_t)(row0 + t) * 2048 + h * 64 + p8];
#pragma unroll
        for (int j = 0; j < 8; ++j)
            Xt[(p8 + j) * XT_STR + t] = v[j];
        bhalf8 zv = *(const bhalf8*)&zxb[(size_t)(row0 + t) * ZX_STR + h * 64 + p8];
        *(bhalf8*)&zS[t * XT_STR + p8] = zv;
    }
    __syncthreads();

    const int wave = threadIdx.x >> 6, lane = threadIdx.x & 63;
    const int lr = lane & 15, lq = lane >> 4;
    const int t0 = wave * 16;
    f32x4 acc1[4], acc2[4];
#pragma unroll
    for (int j = 0; j < 4; ++j) { acc1[j] = (f32x4){0.f,0.f,0.f,0.f}; acc2[j] = acc1[j]; }

#pragma unroll
    for (int kk = 0; kk < 64; kk += 32) {
        bhalf8 af = *(const bhalf8*)&M_bf[(size_t)bhc * 4096 + (t0 + lr) * 64 + kk + lq * 8];
#pragma unroll
        for (int j = 0; j < 4; ++j) {
            bhalf8 bf = *(const bhalf8*)&Xt[(j * 16 + lr) * XT_STR + kk + lq * 8];
            acc1[j] = __builtin_amdgcn_mfma_f32_16x16x32_bf16(af, bf, acc1[j], 0, 0, 0);
        }
    }
#pragma unroll
    for (int kk = 0; kk < 128; kk += 32) {
        bhalf8 af = *(const bhalf8*)&C_bf[(size_t)(row0 + t0 + lr) * 128 + kk + lq * 8];
#pragma unroll
        for (int j = 0; j < 4; ++j) {
            bhalf8 bf = *(const bhalf8*)&hst[(size_t)bhc * 8192 + (j * 16 + lr) * 128 + kk + lq * 8];
            acc2[j] = __builtin_amdgcn_mfma_f32_16x16x32_bf16(af, bf, acc2[j], 0, 0, 0);
        }
    }
    float ex[4];
#pragma unroll
    for (int r = 0; r < 4; ++r) ex[r] = expf(cumg[(size_t)bhc * Q + t0 + lq * 4 + r]);

    float vv[4][4];
    float s2[4] = {0.f, 0.f, 0.f, 0.f};
#pragma unroll
    for (int j = 0; j < 4; ++j)
#pragma unroll
        for (int r = 0; r < 4; ++r) {
            int t = t0 + lq * 4 + r;
            int p = j * 16 + lr;
            float xv = s2f(Xt[p * XT_STR + t]);
            float y = acc1[j][r] + ex[r] * acc2[j][r] + Dh * xv;
            float zz = s2f(zS[t * XT_STR + p]);
            float v = y * (zz / (1.f + expf(-zz)));
            vv[j][r] = v;
            s2[r] += v * v;
        }
    // per-row sum(v^2): reduce over the 16-lane lr group, one atomic per row
#pragma unroll
    for (int r = 0; r < 4; ++r) {
        s2[r] += __shfl_xor(s2[r], 1);
        s2[r] += __shfl_xor(s2[r], 2);
        s2[r] += __shfl_xor(s2[r], 4);
        s2[r] += __shfl_xor(s2[r], 8);
    }
    if (lr == 0)
#pragma unroll
        for (int r = 0; r < 4; ++r)
            atomicAdd(&rowsum[row0 + t0 + lq * 4 + r], s2[r]);

    __syncthreads();       // all zS/Xt reads done
#pragma unroll
    for (int j = 0; j < 4; ++j)
#pragma unroll
        for (int r = 0; r < 4; ++r)
            zS[(t0 + lq * 4 + r) * XT_STR + j * 16 + lr] = f2bs(vv[j][r]);
    __syncthreads();
#pragma unroll
    for (int i = 0; i < 2; ++i) {
        int seg = threadIdx.x + i * 256;
        int t = seg >> 3, p8 = (seg & 7) * 8;
        bhalf8 o = *(const bhalf8*)&zS[t * XT_STR + p8];
        *(bhalf8*)&vbuf[(size_t)(row0 + t) * D_INNER + h * 64 + p8] = o;
    }
}

// ---------------------------------------------------------------------------
// Light scale pass: yg = v * rsqrt(mean(v^2)+eps) * norm_w  (bf16 in/out)
// ---------------------------------------------------------------------------
__global__ __launch_bounds__(256)
void gate_scale(const __hip_bfloat16* __restrict__ vbuf,
                const float* __restrict__ rowsum,
                const void* __restrict__ norm_w,
                const int* __restrict__ flagp,
                __hip_bfloat16* __restrict__ yg)
{
    const int isf = *flagp;
    const int row = blockIdx.x;
    const float scale = rsqrtf(rowsum[row] / (float)D_INNER + 1e-5f);
    const int seg = threadIdx.x;              // 256 segs of 8
    bhalf8 v8 = *(const bhalf8*)&vbuf[(size_t)row * D_INNER + seg * 8];
    bhalf8 o;
#pragma unroll
    for (int j = 0; j < 8; ++j)
        o[j] = f2bs(s2f(v8[j]) * scale * rdin(norm_w, seg * 8 + j, isf));
    *(bhalf8*)&yg[(size_t)row * D_INNER + seg * 8] = o;
}

extern "C" void kernel_launch(void* const* d_in, const int* in_sizes, int n_in,
                              void* d_out, int out_size, void* d_ws, size_t ws_size,
                              hipStream_t stream)
{
    const void* x_raw    = d_in[0];
    const void* inw_raw  = d_in[1];
    const void* convw    = d_in[2];
    const void* convb    = d_in[3];
    const void* dtb      = d_in[4];
    const void* Alog     = d_in[5];
    const void* Dsk      = d_in[6];
    const void* normw    = d_in[7];
    const void* outw_raw = d_in[8];

    char* ws = (char*)d_ws;
    size_t off = 0;
    int* flag = (int*)(ws + off);                      off += 256;
    float* rowsum = (float*)(ws + off);                off += (size_t)NROWS * 4;
    __hip_bfloat16* xb    = (__hip_bfloat16*)(ws+off); off += (size_t)NROWS * D_MODEL * 2;
    __hip_bfloat16* inwb  = (__hip_bfloat16*)(ws+off); off += (size_t)4384 * D_MODEL * 2;
    __hip_bfloat16* outwb = (__hip_bfloat16*)(ws+off); off += (size_t)D_MODEL * D_INNER * 2;
    __hip_bfloat16* zxb   = (__hip_bfloat16*)(ws+off); off += (size_t)NROWS * ZX_STR * 2;
    __hip_bfloat16* xs_bf = (__hip_bfloat16*)(ws+off); off += (size_t)NROWS * 2048 * 2;
    __hip_bfloat16* B_bf  = (__hip_bfloat16*)(ws+off); off += (size_t)NROWS * 128 * 2;
    __hip_bfloat16* C_bf  = (__hip_bfloat16*)(ws+off); off += (size_t)NROWS * 128 * 2;
    float* dtp   = (float*)(ws+off);                   off += (size_t)NROWS * NHEADS * 4;
    float* cumg  = (float*)(ws+off);                   off += (size_t)1024 * Q * 4;
    float* decayg= (float*)(ws+off);                   off += (size_t)1024 * 4;
    __hip_bfloat16* M_bf  = (__hip_bfloat16*)(ws+off); off += (size_t)1024 * 4096 * 2;
    __hip_bfloat16* hst   = (__hip_bfloat16*)(ws+off); off += (size_t)1024 * 8192 * 2;
    __hip_bfloat16* Sb    = (__hip_bfloat16*)(ws+off); off += (size_t)1024 * 8192 * 2;
    // vbuf/yg alias Sb (Sb dead after rec_kernel, before y_kernel writes)
    __hip_bfloat16* vbuf = Sb;
    __hip_bfloat16* yg   = Sb + (size_t)NROWS * D_INNER;

    detect_dtype<<<1, 256, 0, stream>>>((const unsigned short*)x_raw, flag, rowsum);
    to_bf16_all<<<(XN8+WN8+ON8)/256, 256, 0, stream>>>(x_raw, inw_raw, outw_raw,
                                                       xb, inwb, outwb, flag);
    // in_proj: 64x128 tiles -> 34x32 = 1088 blocks
    gemm_bt<0,64,128,1,4><<<dim3(34, 32), 256, 0, stream>>>(
        xb, inwb, zxb, nullptr, nullptr, flag, D_MODEL, ZX_STR);
    // merged conv (blocks 0-255) + dt (blocks 256-511)
    convdt<<<512, 256, 0, stream>>>(zxb, convw, convb, x_raw, inw_raw, dtb, flag,
                                    xs_bf, B_bf, C_bf, dtp);
    chunk_kernel<<<1024, 256, 0, stream>>>(xs_bf, B_bf, C_bf, dtp, Alog, flag,
                                           cumg, decayg, M_bf, Sb);
    rec_kernel<<<512, 256, 0, stream>>>(Sb, decayg, hst);
    y_kernel<<<1024, 256, 0, stream>>>(M_bf, xs_bf, C_bf, hst, cumg, zxb, Dsk,
                                       flag, vbuf, rowsum);
    gate_scale<<<NROWS, 256, 0, stream>>>(vbuf, rowsum, normw, flag, yg);
    // out_proj: 64x64 tiles -> 16x32 = 512 blocks
    gemm_bt<1,64,64,2,2><<<dim3(16, 32), 256, 0, stream>>>(
        yg, outwb, nullptr, x_raw, d_out, flag, D_INNER, D_MODEL);
}